// Round 1
// baseline (2968.012 us; speedup 1.0000x reference)
//
#include <hip/hip_runtime.h>
#include <hip/hip_bf16.h>

#define MK_N 8
#define MK_T 8
#define MK_H 256
#define MK_W 256
#define MK_CO 64
#define MK_EPS 1e-5f

typedef __attribute__((ext_vector_type(8))) short short8;
typedef __attribute__((ext_vector_type(4))) short short4v;
typedef __attribute__((ext_vector_type(4))) float f32x4;

// read element idx from p, which is fp32 (isf32=1) or bf16 (isf32=0)
__device__ __forceinline__ float rdv(const void* p, long idx, int isf32) {
  return isf32 ? ((const float*)p)[idx]
               : __bfloat162float(((const __hip_bfloat16*)p)[idx]);
}

__device__ __forceinline__ short f2bf_s(float f) {
  __hip_bfloat16 b = __float2bfloat16(f);
  union { __hip_bfloat16 b; short s; } u; u.b = b; return u.s;
}
__device__ __forceinline__ float bfu2f(unsigned short s) {
  return __uint_as_float((unsigned)s << 16);
}

// Inline dtype probe on pristine x: bf16 -> sane exponents; fp32 -> ~45% insane.
__device__ __forceinline__ int block_detect_isf(const void* xprobe, int* sflag) {
  if (threadIdx.x < 64) {
    const unsigned short* u16 = (const unsigned short*)xprobe;
    int insane = 0;
#pragma unroll
    for (int j = 0; j < 4; ++j) {
      unsigned short u = u16[threadIdx.x * 4 + j];
      int e = (u >> 7) & 0xFF;
      bool zero = (u & 0x7FFF) == 0;
      if (!(zero || (e >= 0x60 && e <= 0x85))) insane++;
    }
#pragma unroll
    for (int off = 32; off > 0; off >>= 1) insane += __shfl_down(insane, off);
    if (threadIdx.x == 0) *sflag = (insane > 32) ? 1 : 0;
  }
  __syncthreads();
  return *sflag;
}

__global__ void zero128_kernel(float* __restrict__ p) { p[threadIdx.x] = 0.f; }

// ---------------- x (NCHW, fp32|bf16) -> NHWC bf16 ----------------
__global__ __launch_bounds__(256) void x_to_nhwc(const void* __restrict__ x,
                                                 short* __restrict__ xo,
                                                 const void* __restrict__ xprobe) {
  __shared__ float xl[32 * 65];
  __shared__ int sflag;
  int isf = block_detect_isf(xprobe, &sflag);
  int n = blockIdx.z, y = blockIdx.y, x0 = blockIdx.x * 64;
  int tid = threadIdx.x;
  {
    int c = tid >> 3, ch = tid & 7;
    long base = ((long)(n * 32 + c) * 256 + y) * 256 + x0 + ch * 8;
#pragma unroll
    for (int j = 0; j < 8; ++j) xl[c * 65 + ch * 8 + j] = rdv(x, base + j, isf);
  }
  __syncthreads();
  {
    int xi = tid >> 2, cc = tid & 3;
    short8 v;
#pragma unroll
    for (int j = 0; j < 8; ++j) v[j] = f2bf_s(xl[(cc * 8 + j) * 65 + xi]);
    *(short8*)&xo[(((long)(n * 256 + y) * 256) + x0 + xi) * 32 + cc * 8] = v;
  }
}

// ---------------- MFMA implicit-GEMM conv ----------------
// Block: 256 thr (4 waves). Tile: [CO=64] x [4 rows] x [64 cols], sample n.
// 25 shifted GEMMs, K = channels (CI=32: 1 K-chunk; CI=64: 2 c-halves).
// Weights: gate+mix computed in-kernel per shift into double-buffered LDS.
template <int CI, bool FINAL>
__global__ __launch_bounds__(256, 2) void conv_mfma(
    const short* __restrict__ xsrc,   // NHWC bf16 [8][256][256][CI]
    const void* __restrict__ xprobe,
    const void* __restrict__ t, const void* __restrict__ gw, const void* __restrict__ gb,
    const void* __restrict__ w5, const void* __restrict__ w3, const void* __restrict__ w1,
    const void* __restrict__ a3, const void* __restrict__ a5,
    void* __restrict__ outp)          // FINAL ? float* NCHW : short* NHWC bf16
{
  __shared__ short xt[8 * 68 * 40];    // 43520 B, c-half staged, pad 40
  __shared__ short wbuf[2 * 64 * 40];  // 10240 B, double-buffered W panel
  __shared__ float slog[320], sgate[320];
  __shared__ int sflag;

  const int tid = threadIdx.x;
  const int x0 = blockIdx.x * 64;
  const int r0 = blockIdx.y * 4;
  const int n = blockIdx.z;

  const int isf = block_detect_isf(xprobe, &sflag);

  // ---- gates for (n, all o) ----
  for (int eo = tid; eo < 320; eo += 256) {
    int e = eo >> 6, o = eo & 63;
    long row = e * 64 + o;
    float s = rdv(gb, row, isf);
#pragma unroll
    for (int k = 0; k < MK_T; ++k)
      s += rdv(t, n * MK_T + k, isf) * rdv(gw, row * MK_T + k, isf);
    slog[e * 64 + o] = s;
  }
  __syncthreads();
  if (tid < 64) {
    float m = slog[tid];
#pragma unroll
    for (int e = 1; e < 5; ++e) m = fmaxf(m, slog[e * 64 + tid]);
    float tmp[5], sum = 0.f;
#pragma unroll
    for (int e = 0; e < 5; ++e) { tmp[e] = expf(slog[e * 64 + tid] - m); sum += tmp[e]; }
    float inv = 1.f / sum;
#pragma unroll
    for (int e = 0; e < 5; ++e) sgate[tid * 5 + e] = tmp[e] * inv;
  }
  __syncthreads();

  // per-thread mixing role: o = tid>>2, 8 channels at gq*8
  const int mo = tid >> 2, gq = tid & 3;
  float ge[5];
#pragma unroll
  for (int e = 0; e < 5; ++e) ge[e] = sgate[mo * 5 + e];

  const int lane = tid & 63, w = tid >> 6;
  const int quad = lane >> 4, l15 = lane & 15;

  int baseB[4];
#pragma unroll
  for (int p = 0; p < 4; ++p)
    baseB[p] = (w * 68 + p * 16 + l15) * 40 + quad * 8;
  int baseA[4];
#pragma unroll
  for (int ot = 0; ot < 4; ++ot)
    baseA[ot] = (ot * 16 + l15) * 40 + quad * 8;

  f32x4 acc[4][4];
#pragma unroll
  for (int ot = 0; ot < 4; ++ot)
#pragma unroll
    for (int p = 0; p < 4; ++p) acc[ot][p] = f32x4{0.f, 0.f, 0.f, 0.f};

  const int HC = CI / 32;
#pragma unroll 1
  for (int hc = 0; hc < HC; ++hc) {
    const int cbase = hc * 32;

    // preload shift-invariant expert values for this thread's 8 (o,c) slots
    float pw1[8], pa3[8], pa5[8];
#pragma unroll
    for (int j = 0; j < 8; ++j) {
      long oc = (long)mo * CI + cbase + gq * 8 + j;
      pw1[j] = rdv(w1, oc, isf);
      pa3[j] = rdv(a3, oc, isf) * (1.f / 27.f);
      pa5[j] = rdv(a5, oc, isf) * (1.f / 125.f);
    }

    // ---- stage x tile (8 rows x 68 cols x 32 ch) ----
    for (int idx = tid; idx < 8 * 68 * 4; idx += 256) {
      int r = idx / (68 * 4);
      int rem = idx - r * (68 * 4);
      int col = rem >> 2, ch = rem & 3;
      int gy = r0 - 2 + r, gx = x0 - 2 + col;
      short8 v = short8{0, 0, 0, 0, 0, 0, 0, 0};
      if ((unsigned)gy < 256u && (unsigned)gx < 256u)
        v = *(const short8*)&xsrc[(((long)(n * 256 + gy) * 256) + gx) * CI + cbase + ch * 8];
      *(short8*)&xt[(r * 68 + col) * 40 + ch * 8] = v;
    }

    // ---- mix W for shift s into wbuf[buf] ----
    auto mix = [&](int s, int buf) {
      int ky = s / 5, kx = s - ky * 5;
      bool in3 = (ky >= 1 && ky <= 3 && kx >= 1 && kx <= 3);
      short8 pk;
#pragma unroll
      for (int j = 0; j < 8; ++j) {
        long oc = (long)mo * CI + cbase + gq * 8 + j;
        float v = ge[0] * rdv(w5, oc * 25 + s, isf);
        if (in3) {
          v += ge[1] * rdv(w3, oc * 9 + (ky - 1) * 3 + (kx - 1), isf);
          v += ge[3] * pa3[j];
        }
        if (s == 12) v += ge[2] * pw1[j];
        v += ge[4] * pa5[j];
        pk[j] = f2bf_s(v);
      }
      *(short8*)&wbuf[buf * 2560 + mo * 40 + gq * 8] = pk;
    };

    mix(0, 0);
    __syncthreads();

#pragma unroll
    for (int s = 0; s < 25; ++s) {
      if (s < 24) mix(s + 1, (s + 1) & 1);
      const int ky = s / 5, kx = s - ky * 5;
      const int koff = (ky * 68 + kx) * 40;
      const short* wb = &wbuf[(s & 1) * 2560];
      short8 af[4], bf[4];
#pragma unroll
      for (int ot = 0; ot < 4; ++ot) af[ot] = *(const short8*)&wb[baseA[ot]];
#pragma unroll
      for (int p = 0; p < 4; ++p) bf[p] = *(const short8*)&xt[baseB[p] + koff];
#pragma unroll
      for (int ot = 0; ot < 4; ++ot)
#pragma unroll
        for (int p = 0; p < 4; ++p)
          acc[ot][p] = __builtin_amdgcn_mfma_f32_16x16x32_bf16(af[ot], bf[p], acc[ot][p], 0, 0, 0);
      __syncthreads();
    }
  }

  if (FINAL) {
    // fp32 NCHW direct stores
    float* out = (float*)outp;
#pragma unroll
    for (int ot = 0; ot < 4; ++ot)
#pragma unroll
      for (int p = 0; p < 4; ++p)
#pragma unroll
        for (int r = 0; r < 4; ++r) {
          int oo = ot * 16 + quad * 4 + r;
          long off = ((long)(n * 64 + oo) << 16) + (r0 + w) * 256 + x0 + p * 16 + l15;
          out[off] = acc[ot][p][r];
        }
  } else {
    // bf16 NHWC via LDS bounce (alias xt; all reads done: loop ended with barrier)
    short* cbuf = xt;  // need 4*64*72 = 18432 <= 21760
#pragma unroll
    for (int ot = 0; ot < 4; ++ot)
#pragma unroll
      for (int p = 0; p < 4; ++p) {
        short4v pk;
#pragma unroll
        for (int r = 0; r < 4; ++r) pk[r] = f2bf_s(acc[ot][p][r]);
        *(short4v*)&cbuf[(w * 64 + p * 16 + l15) * 72 + ot * 16 + quad * 4] = pk;
      }
    __syncthreads();
    short* hout = (short*)outp;
    for (int idx = tid; idx < 2048; idx += 256) {
      int w2 = idx >> 9, rem = idx & 511;
      int px = rem >> 3, ch = rem & 7;
      short8 v = *(const short8*)&cbuf[(w2 * 64 + px) * 72 + ch * 8];
      *(short8*)&hout[(((long)(n * 256 + r0 + w2) * 256) + x0 + px) * 64 + ch * 8] = v;
    }
  }
}

// ---------------- BN stats over NHWC bf16 (c = idx & 63) ----------------
__global__ __launch_bounds__(256) void stats_nhwc(const unsigned short* __restrict__ h,
                                                  float* __restrict__ stats) {
  __shared__ float rs[256], rq[256];
  int tid = threadIdx.x;
  long base = (long)blockIdx.x * 32768 + tid;
  float s = 0.f, q = 0.f;
#pragma unroll 4
  for (int i = 0; i < 128; ++i) {
    float v = bfu2f(h[base + (long)i * 256]);
    s += v; q += v * v;
  }
  rs[tid] = s; rq[tid] = q;
  __syncthreads();
  if (tid < 64) {
    s = rs[tid] + rs[tid + 64] + rs[tid + 128] + rs[tid + 192];
    q = rq[tid] + rq[tid + 64] + rq[tid + 128] + rq[tid + 192];
    atomicAdd(&stats[tid], s);
    atomicAdd(&stats[64 + tid], q);
  }
}

// ---------------- finalize BN: stats -> per-channel scale/shift ----------------
__global__ void finalize_mode_kernel(const float* __restrict__ stats,
                                     float* __restrict__ params,
                                     const void* __restrict__ gamma,
                                     const void* __restrict__ beta,
                                     const void* __restrict__ xprobe) {
  __shared__ int sflag;
  int isf = block_detect_isf(xprobe, &sflag);
  int o = threadIdx.x;
  if (o < MK_CO) {
    const float M = (float)(MK_N * MK_H * MK_W);
    float mean = stats[o] / M;
    float var = stats[MK_CO + o] / M - mean * mean;
    float inv = rsqrtf(var + MK_EPS);
    float sc = rdv(gamma, o, isf) * inv;
    params[o] = sc;
    params[MK_CO + o] = rdv(beta, o, isf) - mean * sc;
  }
}

// ---------------- in-place BN+ReLU on NHWC bf16 (uint4 = 8 consecutive c) ----------------
__global__ __launch_bounds__(256) void bnrelu_nhwc(uint4* __restrict__ h,
                                                   const float* __restrict__ pr) {
  long i4 = (long)blockIdx.x * 256 + threadIdx.x;
  int c0 = ((int)i4 & 7) * 8;
  uint4 v = h[i4];
  unsigned* u = (unsigned*)&v;
#pragma unroll
  for (int k = 0; k < 4; ++k) {
    int c = c0 + 2 * k;
    float f0 = bfu2f((unsigned short)(u[k] & 0xFFFF));
    float f1 = bfu2f((unsigned short)(u[k] >> 16));
    f0 = fmaxf(fmaf(f0, pr[c], pr[64 + c]), 0.f);
    f1 = fmaxf(fmaf(f1, pr[c + 1], pr[64 + c + 1]), 0.f);
    unsigned lo = (unsigned)(unsigned short)f2bf_s(f0);
    unsigned hi = (unsigned)(unsigned short)f2bf_s(f1);
    u[k] = lo | (hi << 16);
  }
  h[i4] = v;
}

// ---------------- stats over fp32 NCHW ----------------
__global__ __launch_bounds__(256) void stats_pass_kernel(const float* __restrict__ y,
                                                         float* __restrict__ stats) {
  __shared__ float rs[4], rq[4];
  const int b = blockIdx.x;
  const int row = b & (MK_H - 1);
  const int o = (b >> 8) & (MK_CO - 1);
  const int n = b >> 14;
  float v = y[((long)(n * MK_CO + o) * MK_H + row) * MK_W + threadIdx.x];
  float s = v, q = v * v;
#pragma unroll
  for (int off = 32; off > 0; off >>= 1) {
    s += __shfl_down(s, off);
    q += __shfl_down(q, off);
  }
  int lane = threadIdx.x & 63, wv = threadIdx.x >> 6;
  if (lane == 0) { rs[wv] = s; rq[wv] = q; }
  __syncthreads();
  if (threadIdx.x == 0) {
    atomicAdd(&stats[o], rs[0] + rs[1] + rs[2] + rs[3]);
    atomicAdd(&stats[MK_CO + o], rq[0] + rq[1] + rq[2] + rq[3]);
  }
}

// ---------------- in-place BN + ReLU, fp32 NCHW ----------------
__global__ __launch_bounds__(256) void bn_relu_f32(float* __restrict__ y,
                                                   const float* __restrict__ params) {
  long i = (long)blockIdx.x * 256 + threadIdx.x;
  int ch = (int)((i >> 16) & (MK_CO - 1));
  float v = y[i];
  v = fmaxf(fmaf(v, params[ch], params[MK_CO + ch]), 0.f);
  y[i] = v;
}

extern "C" void kernel_launch(void* const* d_in, const int* in_sizes, int n_in,
                              void* d_out, int out_size, void* d_ws, size_t ws_size,
                              hipStream_t stream) {
  const void* x     = d_in[0];
  const void* t     = d_in[1];
  const void* w5_1  = d_in[2];
  const void* w3_1  = d_in[3];
  const void* w1_1  = d_in[4];
  const void* a3_1  = d_in[5];
  const void* a5_1  = d_in[6];
  const void* gw_1  = d_in[7];
  const void* gb_1  = d_in[8];
  const void* gamma_1 = d_in[9];
  const void* beta_1  = d_in[10];
  const void* w5_2  = d_in[11];
  const void* w3_2  = d_in[12];
  const void* w1_2  = d_in[13];
  const void* a3_2  = d_in[14];
  const void* a5_2  = d_in[15];
  const void* gw_2  = d_in[16];
  const void* gb_2  = d_in[17];
  const void* gamma_2 = d_in[18];
  const void* beta_2  = d_in[19];

  // ws: EXACTLY 64 MiB — h (NHWC bf16). Head reused for layer-2 stats after conv2.
  short* h = (short*)d_ws;
  float* st2 = (float*)d_ws;
  float* pr2 = (float*)d_ws + 128;

  // d_out doubles as scratch until conv2 overwrites it:
  short* x_nhwc = (short*)d_out;                          // 33,554,432 B
  float* st1 = (float*)((char*)d_out + 33554432);
  float* pr1 = st1 + 128;
  float* out = (float*)d_out;                             // final fp32 NCHW

  // ---- layer 1 ----
  x_to_nhwc<<<dim3(4, 256, 8), 256, 0, stream>>>(x, x_nhwc, x);
  zero128_kernel<<<1, 128, 0, stream>>>(st1);
  conv_mfma<32, false><<<dim3(4, 64, 8), 256, 0, stream>>>(
      x_nhwc, x, t, gw_1, gb_1, w5_1, w3_1, w1_1, a3_1, a5_1, h);
  stats_nhwc<<<1024, 256, 0, stream>>>((const unsigned short*)h, st1);
  finalize_mode_kernel<<<1, 64, 0, stream>>>(st1, pr1, gamma_1, beta_1, x);
  bnrelu_nhwc<<<16384, 256, 0, stream>>>((uint4*)h, pr1);

  // ---- layer 2 ----
  conv_mfma<64, true><<<dim3(4, 64, 8), 256, 0, stream>>>(
      h, x, t, gw_2, gb_2, w5_2, w3_2, w1_2, a3_2, a5_2, out);
  zero128_kernel<<<1, 128, 0, stream>>>(st2);
  stats_pass_kernel<<<MK_N * MK_CO * MK_H, 256, 0, stream>>>(out, st2);
  finalize_mode_kernel<<<1, 64, 0, stream>>>(st2, pr2, gamma_2, beta_2, x);
  bn_relu_f32<<<MK_N * MK_CO * MK_H, 256, 0, stream>>>(out, pr2);
}

// Round 2
// 1550.495 us; speedup vs baseline: 1.9142x; 1.9142x over previous
//
#include <hip/hip_runtime.h>
#include <hip/hip_bf16.h>

#define MK_N 8
#define MK_T 8
#define MK_H 256
#define MK_W 256
#define MK_CO 64
#define MK_EPS 1e-5f

typedef __attribute__((ext_vector_type(8))) short short8;
typedef __attribute__((ext_vector_type(4))) short short4v;
typedef __attribute__((ext_vector_type(4))) float f32x4;

// read element idx from p, which is fp32 (isf32=1) or bf16 (isf32=0)
__device__ __forceinline__ float rdv(const void* p, long idx, int isf32) {
  return isf32 ? ((const float*)p)[idx]
               : __bfloat162float(((const __hip_bfloat16*)p)[idx]);
}

__device__ __forceinline__ short f2bf_s(float f) {
  __hip_bfloat16 b = __float2bfloat16(f);
  union { __hip_bfloat16 b; short s; } u; u.b = b; return u.s;
}
__device__ __forceinline__ float bfu2f(unsigned short s) {
  return __uint_as_float((unsigned)s << 16);
}

// Inline dtype probe on pristine x: bf16 -> sane exponents; fp32 -> ~45% insane.
__device__ __forceinline__ int block_detect_isf(const void* xprobe, int* sflag) {
  if (threadIdx.x < 64) {
    const unsigned short* u16 = (const unsigned short*)xprobe;
    int insane = 0;
#pragma unroll
    for (int j = 0; j < 4; ++j) {
      unsigned short u = u16[threadIdx.x * 4 + j];
      int e = (u >> 7) & 0xFF;
      bool zero = (u & 0x7FFF) == 0;
      if (!(zero || (e >= 0x60 && e <= 0x85))) insane++;
    }
#pragma unroll
    for (int off = 32; off > 0; off >>= 1) insane += __shfl_down(insane, off);
    if (threadIdx.x == 0) *sflag = (insane > 32) ? 1 : 0;
  }
  __syncthreads();
  return *sflag;
}

__global__ void zero128_kernel(float* __restrict__ p) { p[threadIdx.x] = 0.f; }

// ---------------- x (NCHW, fp32|bf16) -> NHWC bf16 ----------------
__global__ __launch_bounds__(256) void x_to_nhwc(const void* __restrict__ x,
                                                 short* __restrict__ xo,
                                                 const void* __restrict__ xprobe) {
  __shared__ float xl[32 * 65];
  __shared__ int sflag;
  int isf = block_detect_isf(xprobe, &sflag);
  int n = blockIdx.z, y = blockIdx.y, x0 = blockIdx.x * 64;
  int tid = threadIdx.x;
  {
    int c = tid >> 3, ch = tid & 7;
    long base = ((long)(n * 32 + c) * 256 + y) * 256 + x0 + ch * 8;
#pragma unroll
    for (int j = 0; j < 8; ++j) xl[c * 65 + ch * 8 + j] = rdv(x, base + j, isf);
  }
  __syncthreads();
  {
    int xi = tid >> 2, cc = tid & 3;
    short8 v;
#pragma unroll
    for (int j = 0; j < 8; ++j) v[j] = f2bf_s(xl[(cc * 8 + j) * 65 + xi]);
    *(short8*)&xo[(((long)(n * 256 + y) * 256) + x0 + xi) * 32 + cc * 8] = v;
  }
}

// ---------------- panel precompute: gates + mixed weights, once per (n,s) ----------------
// Panel layout: [n][hc][s][o=64][c=32] bf16  (exactly the MFMA A-fragment order)
// grid: (25 s, 8 n), 256 threads; thread (mo=tid>>2, gq=tid&3) covers o=mo, c=gq*8..+7.
template <int CI>
__global__ __launch_bounds__(256) void make_panels(
    const void* __restrict__ t, const void* __restrict__ gw, const void* __restrict__ gb,
    const void* __restrict__ w5, const void* __restrict__ w3, const void* __restrict__ w1,
    const void* __restrict__ a3, const void* __restrict__ a5,
    short* __restrict__ pan, const void* __restrict__ xprobe) {
  __shared__ float slog[320], sgate[320];
  __shared__ int sflag;
  const int s = blockIdx.x, n = blockIdx.y;
  const int tid = threadIdx.x;
  const int isf = block_detect_isf(xprobe, &sflag);

  // logits for (n, all e,o) — identical math to previous in-conv version
  for (int eo = tid; eo < 320; eo += 256) {
    int e = eo >> 6, o = eo & 63;
    long row = e * 64 + o;
    float sacc = rdv(gb, row, isf);
#pragma unroll
    for (int k = 0; k < MK_T; ++k)
      sacc += rdv(t, n * MK_T + k, isf) * rdv(gw, row * MK_T + k, isf);
    slog[e * 64 + o] = sacc;
  }
  __syncthreads();
  if (tid < 64) {
    float m = slog[tid];
#pragma unroll
    for (int e = 1; e < 5; ++e) m = fmaxf(m, slog[e * 64 + tid]);
    float tmp[5], sum = 0.f;
#pragma unroll
    for (int e = 0; e < 5; ++e) { tmp[e] = expf(slog[e * 64 + tid] - m); sum += tmp[e]; }
    float inv = 1.f / sum;
#pragma unroll
    for (int e = 0; e < 5; ++e) sgate[tid * 5 + e] = tmp[e] * inv;
  }
  __syncthreads();

  const int mo = tid >> 2, gq = tid & 3;
  float ge[5];
#pragma unroll
  for (int e = 0; e < 5; ++e) ge[e] = sgate[mo * 5 + e];

  const int ky = s / 5, kx = s - ky * 5;
  const bool in3 = (ky >= 1 && ky <= 3 && kx >= 1 && kx <= 3);
  const int HC = CI / 32;
#pragma unroll
  for (int hc = 0; hc < HC; ++hc) {
    short8 pk;
#pragma unroll
    for (int j = 0; j < 8; ++j) {
      long oc = (long)mo * CI + hc * 32 + gq * 8 + j;
      float pa3 = rdv(a3, oc, isf) * (1.f / 27.f);
      float pa5 = rdv(a5, oc, isf) * (1.f / 125.f);
      float v = ge[0] * rdv(w5, oc * 25 + s, isf);
      if (in3) {
        v += ge[1] * rdv(w3, oc * 9 + (ky - 1) * 3 + (kx - 1), isf);
        v += ge[3] * pa3;
      }
      if (s == 12) v += ge[2] * rdv(w1, oc, isf);
      v += ge[4] * pa5;
      pk[j] = f2bf_s(v);
    }
    *(short8*)&pan[((((long)n * HC + hc) * 25 + s) * 64 + mo) * 32 + gq * 8] = pk;
  }
}

// ---------------- trivial 16B copy ----------------
__global__ __launch_bounds__(256) void copy16(const short8* __restrict__ src,
                                              short8* __restrict__ dst, int n16) {
  int i = blockIdx.x * 256 + threadIdx.x;
  if (i < n16) dst[i] = src[i];
}

// ---------------- MFMA implicit-GEMM conv (barrier-free shift loop) ----------------
// Block: 256 thr (4 waves). Tile: [CO=64] x [4 rows] x [64 cols], sample n.
// 25 shifted GEMMs; A-fragments read coalesced from precomputed global panel.
template <int CI, bool FINAL>
__global__ __launch_bounds__(256, 3) void conv_mfma(
    const short* __restrict__ xsrc,   // NHWC bf16 [8][256][256][CI]
    const short* __restrict__ pan,    // [n][hc][s][64][32] bf16
    void* __restrict__ outp,          // FINAL ? float* NCHW : short* NHWC bf16
    int nbase)
{
  __shared__ short xt[8 * 68 * 40];    // 43520 B, c-half staged, pad 40

  const int tid = threadIdx.x;
  const int x0 = blockIdx.x * 64;
  const int r0 = blockIdx.y * 4;
  const int n = blockIdx.z + nbase;

  const int lane = tid & 63, w = tid >> 6;
  const int quad = lane >> 4, l15 = lane & 15;

  int baseB[4];
#pragma unroll
  for (int p = 0; p < 4; ++p)
    baseB[p] = (w * 68 + p * 16 + l15) * 40 + quad * 8;
  int aoff[4];
#pragma unroll
  for (int ot = 0; ot < 4; ++ot)
    aoff[ot] = (ot * 16 + l15) * 32 + quad * 8;

  f32x4 acc[4][4];
#pragma unroll
  for (int ot = 0; ot < 4; ++ot)
#pragma unroll
    for (int p = 0; p < 4; ++p) acc[ot][p] = f32x4{0.f, 0.f, 0.f, 0.f};

  const int HC = CI / 32;
#pragma unroll 1
  for (int hc = 0; hc < HC; ++hc) {
    const int cbase = hc * 32;
    __syncthreads();  // xt WAR protection (needed for hc>0)

    // ---- stage x tile (8 rows x 68 cols x 32 ch) ----
    for (int idx = tid; idx < 8 * 68 * 4; idx += 256) {
      int r = idx / (68 * 4);
      int rem = idx - r * (68 * 4);
      int col = rem >> 2, ch = rem & 3;
      int gy = r0 - 2 + r, gx = x0 - 2 + col;
      short8 v = short8{0, 0, 0, 0, 0, 0, 0, 0};
      if ((unsigned)gy < 256u && (unsigned)gx < 256u)
        v = *(const short8*)&xsrc[(((long)(n * 256 + gy) * 256) + gx) * CI + cbase + ch * 8];
      *(short8*)&xt[(r * 68 + col) * 40 + ch * 8] = v;
    }
    __syncthreads();

    const short* ps = pan + (((long)n * HC + hc) * 25) * 2048;
#pragma unroll
    for (int s = 0; s < 25; ++s) {
      const int ky = s / 5, kx = s - ky * 5;
      const int koff = (ky * 68 + kx) * 40;
      short8 af[4], bf[4];
#pragma unroll
      for (int ot = 0; ot < 4; ++ot) af[ot] = *(const short8*)&ps[s * 2048 + aoff[ot]];
#pragma unroll
      for (int p = 0; p < 4; ++p) bf[p] = *(const short8*)&xt[baseB[p] + koff];
#pragma unroll
      for (int ot = 0; ot < 4; ++ot)
#pragma unroll
        for (int p = 0; p < 4; ++p)
          acc[ot][p] = __builtin_amdgcn_mfma_f32_16x16x32_bf16(af[ot], bf[p], acc[ot][p], 0, 0, 0);
    }
  }

  if (FINAL) {
    // fp32 NCHW direct stores
    float* out = (float*)outp;
#pragma unroll
    for (int ot = 0; ot < 4; ++ot)
#pragma unroll
      for (int p = 0; p < 4; ++p)
#pragma unroll
        for (int r = 0; r < 4; ++r) {
          int oo = ot * 16 + quad * 4 + r;
          long off = ((long)(n * 64 + oo) << 16) + (r0 + w) * 256 + x0 + p * 16 + l15;
          out[off] = acc[ot][p][r];
        }
  } else {
    __syncthreads();  // all xt reads done before aliasing
    // bf16 NHWC via LDS bounce (alias xt)
    short* cbuf = xt;  // need 4*64*72 = 18432 shorts <= 21760
#pragma unroll
    for (int ot = 0; ot < 4; ++ot)
#pragma unroll
      for (int p = 0; p < 4; ++p) {
        short4v pk;
#pragma unroll
        for (int r = 0; r < 4; ++r) pk[r] = f2bf_s(acc[ot][p][r]);
        *(short4v*)&cbuf[(w * 64 + p * 16 + l15) * 72 + ot * 16 + quad * 4] = pk;
      }
    __syncthreads();
    short* hout = (short*)outp;
    for (int idx = tid; idx < 2048; idx += 256) {
      int w2 = idx >> 9, rem = idx & 511;
      int px = rem >> 3, ch = rem & 7;
      short8 v = *(const short8*)&cbuf[(w2 * 64 + px) * 72 + ch * 8];
      *(short8*)&hout[(((long)(n * 256 + r0 + w2) * 256) + x0 + px) * 64 + ch * 8] = v;
    }
  }
}

// ---------------- BN stats over NHWC bf16 (c = idx & 63) ----------------
__global__ __launch_bounds__(256) void stats_nhwc(const unsigned short* __restrict__ h,
                                                  float* __restrict__ stats) {
  __shared__ float rs[256], rq[256];
  int tid = threadIdx.x;
  long base = (long)blockIdx.x * 32768 + tid;
  float s = 0.f, q = 0.f;
#pragma unroll 4
  for (int i = 0; i < 128; ++i) {
    float v = bfu2f(h[base + (long)i * 256]);
    s += v; q += v * v;
  }
  rs[tid] = s; rq[tid] = q;
  __syncthreads();
  if (tid < 64) {
    s = rs[tid] + rs[tid + 64] + rs[tid + 128] + rs[tid + 192];
    q = rq[tid] + rq[tid + 64] + rq[tid + 128] + rq[tid + 192];
    atomicAdd(&stats[tid], s);
    atomicAdd(&stats[64 + tid], q);
  }
}

// ---------------- finalize BN: stats -> per-channel scale/shift ----------------
__global__ void finalize_mode_kernel(const float* __restrict__ stats,
                                     float* __restrict__ params,
                                     const void* __restrict__ gamma,
                                     const void* __restrict__ beta,
                                     const void* __restrict__ xprobe) {
  __shared__ int sflag;
  int isf = block_detect_isf(xprobe, &sflag);
  int o = threadIdx.x;
  if (o < MK_CO) {
    const float M = (float)(MK_N * MK_H * MK_W);
    float mean = stats[o] / M;
    float var = stats[MK_CO + o] / M - mean * mean;
    float inv = rsqrtf(var + MK_EPS);
    float sc = rdv(gamma, o, isf) * inv;
    params[o] = sc;
    params[MK_CO + o] = rdv(beta, o, isf) - mean * sc;
  }
}

// ---------------- in-place BN+ReLU on NHWC bf16 (uint4 = 8 consecutive c) ----------------
__global__ __launch_bounds__(256) void bnrelu_nhwc(uint4* __restrict__ h,
                                                   const float* __restrict__ pr) {
  long i4 = (long)blockIdx.x * 256 + threadIdx.x;
  int c0 = ((int)i4 & 7) * 8;
  uint4 v = h[i4];
  unsigned* u = (unsigned*)&v;
#pragma unroll
  for (int k = 0; k < 4; ++k) {
    int c = c0 + 2 * k;
    float f0 = bfu2f((unsigned short)(u[k] & 0xFFFF));
    float f1 = bfu2f((unsigned short)(u[k] >> 16));
    f0 = fmaxf(fmaf(f0, pr[c], pr[64 + c]), 0.f);
    f1 = fmaxf(fmaf(f1, pr[c + 1], pr[64 + c + 1]), 0.f);
    unsigned lo = (unsigned)(unsigned short)f2bf_s(f0);
    unsigned hi = (unsigned)(unsigned short)f2bf_s(f1);
    u[k] = lo | (hi << 16);
  }
  h[i4] = v;
}

// ---------------- stats over fp32 NCHW ----------------
__global__ __launch_bounds__(256) void stats_pass_kernel(const float* __restrict__ y,
                                                         float* __restrict__ stats) {
  __shared__ float rs[4], rq[4];
  const int b = blockIdx.x;
  const int row = b & (MK_H - 1);
  const int o = (b >> 8) & (MK_CO - 1);
  const int n = b >> 14;
  float v = y[((long)(n * MK_CO + o) * MK_H + row) * MK_W + threadIdx.x];
  float s = v, q = v * v;
#pragma unroll
  for (int off = 32; off > 0; off >>= 1) {
    s += __shfl_down(s, off);
    q += __shfl_down(q, off);
  }
  int lane = threadIdx.x & 63, wv = threadIdx.x >> 6;
  if (lane == 0) { rs[wv] = s; rq[wv] = q; }
  __syncthreads();
  if (threadIdx.x == 0) {
    atomicAdd(&stats[o], rs[0] + rs[1] + rs[2] + rs[3]);
    atomicAdd(&stats[MK_CO + o], rq[0] + rq[1] + rq[2] + rq[3]);
  }
}

// ---------------- in-place BN + ReLU, fp32 NCHW ----------------
__global__ __launch_bounds__(256) void bn_relu_f32(float* __restrict__ y,
                                                   const float* __restrict__ params) {
  long i = (long)blockIdx.x * 256 + threadIdx.x;
  int ch = (int)((i >> 16) & (MK_CO - 1));
  float v = y[i];
  v = fmaxf(fmaf(v, params[ch], params[MK_CO + ch]), 0.f);
  y[i] = v;
}

extern "C" void kernel_launch(void* const* d_in, const int* in_sizes, int n_in,
                              void* d_out, int out_size, void* d_ws, size_t ws_size,
                              hipStream_t stream) {
  const void* x     = d_in[0];
  const void* t     = d_in[1];
  const void* w5_1  = d_in[2];
  const void* w3_1  = d_in[3];
  const void* w1_1  = d_in[4];
  const void* a3_1  = d_in[5];
  const void* a5_1  = d_in[6];
  const void* gw_1  = d_in[7];
  const void* gb_1  = d_in[8];
  const void* gamma_1 = d_in[9];
  const void* beta_1  = d_in[10];
  const void* w5_2  = d_in[11];
  const void* w3_2  = d_in[12];
  const void* w1_2  = d_in[13];
  const void* a3_2  = d_in[14];
  const void* a5_2  = d_in[15];
  const void* gw_2  = d_in[16];
  const void* gb_2  = d_in[17];
  const void* gamma_2 = d_in[18];
  const void* beta_2  = d_in[19];

  // Memory map (d_out = 128 MiB, ws = 64 MiB):
  //   d_out[0:32M)   : x_nhwc (dead after conv1; overwritten by conv2A output)
  //   d_out[32M]     : st1/pr1 (dead after bnrelu1)
  //   d_out[34M]     : P1 panels, 819200 B (dead after conv1)
  //   d_out[100M]    : P2 panels, 1638400 B (read by conv2A which writes [0,64M) only)
  //   d_out[0:128M)  : final fp32 NCHW output (conv2A writes n0-3, conv2B writes n4-7)
  //   ws[0:64M)      : h bf16 NHWC. After conv2A, ws[0:32M) (n0-3) is dead:
  //   ws[0]          : st2/pr2        ws[2M]: P2 copy for conv2B
  char* dob = (char*)d_out;
  short* x_nhwc = (short*)d_out;
  float* st1 = (float*)(dob + 33554432);
  float* pr1 = st1 + 128;
  short* P1  = (short*)(dob + 35651584);
  short* P2  = (short*)(dob + 104857600);
  float* out = (float*)d_out;

  short* h   = (short*)d_ws;
  float* st2 = (float*)d_ws;
  float* pr2 = st2 + 128;
  short* P2c = (short*)d_ws + 1048576;  // ws + 2 MiB

  // ---- panels (both layers depend only on t + weight inputs) ----
  make_panels<32><<<dim3(25, 8), 256, 0, stream>>>(t, gw_1, gb_1, w5_1, w3_1, w1_1, a3_1, a5_1, P1, x);
  make_panels<64><<<dim3(25, 8), 256, 0, stream>>>(t, gw_2, gb_2, w5_2, w3_2, w1_2, a3_2, a5_2, P2, x);

  // ---- layer 1 ----
  x_to_nhwc<<<dim3(4, 256, 8), 256, 0, stream>>>(x, x_nhwc, x);
  zero128_kernel<<<1, 128, 0, stream>>>(st1);
  conv_mfma<32, false><<<dim3(4, 64, 8), 256, 0, stream>>>(x_nhwc, P1, h, 0);
  stats_nhwc<<<1024, 256, 0, stream>>>((const unsigned short*)h, st1);
  finalize_mode_kernel<<<1, 64, 0, stream>>>(st1, pr1, gamma_1, beta_1, x);
  bnrelu_nhwc<<<16384, 256, 0, stream>>>((uint4*)h, pr1);

  // ---- layer 2 (split so panels are never read after being overwritten) ----
  conv_mfma<64, true><<<dim3(4, 64, 4), 256, 0, stream>>>(h, P2, out, 0);
  copy16<<<400, 256, 0, stream>>>((const short8*)P2, (short8*)P2c, 102400);
  conv_mfma<64, true><<<dim3(4, 64, 4), 256, 0, stream>>>(h, P2c, out, 4);
  zero128_kernel<<<1, 128, 0, stream>>>(st2);
  stats_pass_kernel<<<MK_N * MK_CO * MK_H, 256, 0, stream>>>(out, st2);
  finalize_mode_kernel<<<1, 64, 0, stream>>>(st2, pr2, gamma_2, beta_2, x);
  bn_relu_f32<<<MK_N * MK_CO * MK_H, 256, 0, stream>>>(out, pr2);
}

// Round 3
// 617.180 us; speedup vs baseline: 4.8090x; 2.5122x over previous
//
#include <hip/hip_runtime.h>
#include <hip/hip_bf16.h>

#define MK_N 8
#define MK_T 8
#define MK_H 256
#define MK_W 256
#define MK_CO 64
#define MK_EPS 1e-5f

typedef __attribute__((ext_vector_type(8))) short short8;
typedef __attribute__((ext_vector_type(4))) short short4v;
typedef __attribute__((ext_vector_type(4))) float f32x4;

// read element idx from p, which is fp32 (isf32=1) or bf16 (isf32=0)
__device__ __forceinline__ float rdv(const void* p, long idx, int isf32) {
  return isf32 ? ((const float*)p)[idx]
               : __bfloat162float(((const __hip_bfloat16*)p)[idx]);
}

__device__ __forceinline__ short f2bf_s(float f) {
  __hip_bfloat16 b = __float2bfloat16(f);
  union { __hip_bfloat16 b; short s; } u; u.b = b; return u.s;
}
__device__ __forceinline__ float bfu2f(unsigned short s) {
  return __uint_as_float((unsigned)s << 16);
}

// Inline dtype probe on pristine x: bf16 -> sane exponents; fp32 -> ~45% insane.
__device__ __forceinline__ int block_detect_isf(const void* xprobe, int* sflag) {
  if (threadIdx.x < 64) {
    const unsigned short* u16 = (const unsigned short*)xprobe;
    int insane = 0;
#pragma unroll
    for (int j = 0; j < 4; ++j) {
      unsigned short u = u16[threadIdx.x * 4 + j];
      int e = (u >> 7) & 0xFF;
      bool zero = (u & 0x7FFF) == 0;
      if (!(zero || (e >= 0x60 && e <= 0x85))) insane++;
    }
#pragma unroll
    for (int off = 32; off > 0; off >>= 1) insane += __shfl_down(insane, off);
    if (threadIdx.x == 0) *sflag = (insane > 32) ? 1 : 0;
  }
  __syncthreads();
  return *sflag;
}

__global__ void zero128_kernel(float* __restrict__ p) { p[threadIdx.x] = 0.f; }

// ---------------- x (NCHW, fp32|bf16) -> NHWC bf16 ----------------
__global__ __launch_bounds__(256) void x_to_nhwc(const void* __restrict__ x,
                                                 short* __restrict__ xo,
                                                 const void* __restrict__ xprobe) {
  __shared__ float xl[32 * 65];
  __shared__ int sflag;
  int isf = block_detect_isf(xprobe, &sflag);
  int n = blockIdx.z, y = blockIdx.y, x0 = blockIdx.x * 64;
  int tid = threadIdx.x;
  {
    int c = tid >> 3, ch = tid & 7;
    long base = ((long)(n * 32 + c) * 256 + y) * 256 + x0 + ch * 8;
#pragma unroll
    for (int j = 0; j < 8; ++j) xl[c * 65 + ch * 8 + j] = rdv(x, base + j, isf);
  }
  __syncthreads();
  {
    int xi = tid >> 2, cc = tid & 3;
    short8 v;
#pragma unroll
    for (int j = 0; j < 8; ++j) v[j] = f2bf_s(xl[(cc * 8 + j) * 65 + xi]);
    *(short8*)&xo[(((long)(n * 256 + y) * 256) + x0 + xi) * 32 + cc * 8] = v;
  }
}

// ---------------- panel precompute: gates + mixed weights, once per (n,s) ----------------
// Panel layout: [n][hc][s][o=64][c=32] bf16  (exactly the MFMA A-fragment order)
// grid: (25 s, 8 n), 256 threads; thread (mo=tid>>2, gq=tid&3) covers o=mo, c=gq*8..+7.
template <int CI>
__global__ __launch_bounds__(256) void make_panels(
    const void* __restrict__ t, const void* __restrict__ gw, const void* __restrict__ gb,
    const void* __restrict__ w5, const void* __restrict__ w3, const void* __restrict__ w1,
    const void* __restrict__ a3, const void* __restrict__ a5,
    short* __restrict__ pan, const void* __restrict__ xprobe) {
  __shared__ float slog[320], sgate[320];
  __shared__ int sflag;
  const int s = blockIdx.x, n = blockIdx.y;
  const int tid = threadIdx.x;
  const int isf = block_detect_isf(xprobe, &sflag);

  // logits for (n, all e,o)
  for (int eo = tid; eo < 320; eo += 256) {
    int e = eo >> 6, o = eo & 63;
    long row = e * 64 + o;
    float sacc = rdv(gb, row, isf);
#pragma unroll
    for (int k = 0; k < MK_T; ++k)
      sacc += rdv(t, n * MK_T + k, isf) * rdv(gw, row * MK_T + k, isf);
    slog[e * 64 + o] = sacc;
  }
  __syncthreads();
  if (tid < 64) {
    float m = slog[tid];
#pragma unroll
    for (int e = 1; e < 5; ++e) m = fmaxf(m, slog[e * 64 + tid]);
    float tmp[5], sum = 0.f;
#pragma unroll
    for (int e = 0; e < 5; ++e) { tmp[e] = expf(slog[e * 64 + tid] - m); sum += tmp[e]; }
    float inv = 1.f / sum;
#pragma unroll
    for (int e = 0; e < 5; ++e) sgate[tid * 5 + e] = tmp[e] * inv;
  }
  __syncthreads();

  const int mo = tid >> 2, gq = tid & 3;
  float ge[5];
#pragma unroll
  for (int e = 0; e < 5; ++e) ge[e] = sgate[mo * 5 + e];

  const int ky = s / 5, kx = s - ky * 5;
  const bool in3 = (ky >= 1 && ky <= 3 && kx >= 1 && kx <= 3);
  const int HC = CI / 32;
#pragma unroll
  for (int hc = 0; hc < HC; ++hc) {
    short8 pk;
#pragma unroll
    for (int j = 0; j < 8; ++j) {
      long oc = (long)mo * CI + hc * 32 + gq * 8 + j;
      float pa3 = rdv(a3, oc, isf) * (1.f / 27.f);
      float pa5 = rdv(a5, oc, isf) * (1.f / 125.f);
      float v = ge[0] * rdv(w5, oc * 25 + s, isf);
      if (in3) {
        v += ge[1] * rdv(w3, oc * 9 + (ky - 1) * 3 + (kx - 1), isf);
        v += ge[3] * pa3;
      }
      if (s == 12) v += ge[2] * rdv(w1, oc, isf);
      v += ge[4] * pa5;
      pk[j] = f2bf_s(v);
    }
    *(short8*)&pan[((((long)n * HC + hc) * 25 + s) * 64 + mo) * 32 + gq * 8] = pk;
  }
}

// ---------------- trivial 16B copy ----------------
__global__ __launch_bounds__(256) void copy16(const short8* __restrict__ src,
                                              short8* __restrict__ dst, int n16) {
  int i = blockIdx.x * 256 + threadIdx.x;
  if (i < n16) dst[i] = src[i];
}

// ---------------- MFMA implicit-GEMM conv (barrier-free shift loop) ----------------
template <int CI, bool FINAL>
__global__ __launch_bounds__(256, 3) void conv_mfma(
    const short* __restrict__ xsrc,   // NHWC bf16 [8][256][256][CI]
    const short* __restrict__ pan,    // [n][hc][s][64][32] bf16
    void* __restrict__ outp,          // FINAL ? float* NCHW : short* NHWC bf16
    int nbase)
{
  __shared__ short xt[8 * 68 * 40];    // 43520 B, c-half staged, pad 40

  const int tid = threadIdx.x;
  const int x0 = blockIdx.x * 64;
  const int r0 = blockIdx.y * 4;
  const int n = blockIdx.z + nbase;

  const int lane = tid & 63, w = tid >> 6;
  const int quad = lane >> 4, l15 = lane & 15;

  int baseB[4];
#pragma unroll
  for (int p = 0; p < 4; ++p)
    baseB[p] = (w * 68 + p * 16 + l15) * 40 + quad * 8;
  int aoff[4];
#pragma unroll
  for (int ot = 0; ot < 4; ++ot)
    aoff[ot] = (ot * 16 + l15) * 32 + quad * 8;

  f32x4 acc[4][4];
#pragma unroll
  for (int ot = 0; ot < 4; ++ot)
#pragma unroll
    for (int p = 0; p < 4; ++p) acc[ot][p] = f32x4{0.f, 0.f, 0.f, 0.f};

  const int HC = CI / 32;
#pragma unroll 1
  for (int hc = 0; hc < HC; ++hc) {
    const int cbase = hc * 32;
    __syncthreads();  // xt WAR protection (needed for hc>0)

    // ---- stage x tile (8 rows x 68 cols x 32 ch) ----
    for (int idx = tid; idx < 8 * 68 * 4; idx += 256) {
      int r = idx / (68 * 4);
      int rem = idx - r * (68 * 4);
      int col = rem >> 2, ch = rem & 3;
      int gy = r0 - 2 + r, gx = x0 - 2 + col;
      short8 v = short8{0, 0, 0, 0, 0, 0, 0, 0};
      if ((unsigned)gy < 256u && (unsigned)gx < 256u)
        v = *(const short8*)&xsrc[(((long)(n * 256 + gy) * 256) + gx) * CI + cbase + ch * 8];
      *(short8*)&xt[(r * 68 + col) * 40 + ch * 8] = v;
    }
    __syncthreads();

    const short* ps = pan + (((long)n * HC + hc) * 25) * 2048;
#pragma unroll
    for (int s = 0; s < 25; ++s) {
      const int ky = s / 5, kx = s - ky * 5;
      const int koff = (ky * 68 + kx) * 40;
      short8 af[4], bf[4];
#pragma unroll
      for (int ot = 0; ot < 4; ++ot) af[ot] = *(const short8*)&ps[s * 2048 + aoff[ot]];
#pragma unroll
      for (int p = 0; p < 4; ++p) bf[p] = *(const short8*)&xt[baseB[p] + koff];
#pragma unroll
      for (int ot = 0; ot < 4; ++ot)
#pragma unroll
        for (int p = 0; p < 4; ++p)
          acc[ot][p] = __builtin_amdgcn_mfma_f32_16x16x32_bf16(af[ot], bf[p], acc[ot][p], 0, 0, 0);
    }
  }

  if (FINAL) {
    // fp32 NCHW direct stores
    float* out = (float*)outp;
#pragma unroll
    for (int ot = 0; ot < 4; ++ot)
#pragma unroll
      for (int p = 0; p < 4; ++p)
#pragma unroll
        for (int r = 0; r < 4; ++r) {
          int oo = ot * 16 + quad * 4 + r;
          long off = ((long)(n * 64 + oo) << 16) + (r0 + w) * 256 + x0 + p * 16 + l15;
          out[off] = acc[ot][p][r];
        }
  } else {
    __syncthreads();  // all xt reads done before aliasing
    // bf16 NHWC via LDS bounce (alias xt)
    short* cbuf = xt;  // need 4*64*72 = 18432 shorts <= 21760
#pragma unroll
    for (int ot = 0; ot < 4; ++ot)
#pragma unroll
      for (int p = 0; p < 4; ++p) {
        short4v pk;
#pragma unroll
        for (int r = 0; r < 4; ++r) pk[r] = f2bf_s(acc[ot][p][r]);
        *(short4v*)&cbuf[(w * 64 + p * 16 + l15) * 72 + ot * 16 + quad * 4] = pk;
      }
    __syncthreads();
    short* hout = (short*)outp;
    for (int idx = tid; idx < 2048; idx += 256) {
      int w2 = idx >> 9, rem = idx & 511;
      int px = rem >> 3, ch = rem & 7;
      short8 v = *(const short8*)&cbuf[(w2 * 64 + px) * 72 + ch * 8];
      *(short8*)&hout[(((long)(n * 256 + r0 + w2) * 256) + x0 + px) * 64 + ch * 8] = v;
    }
  }
}

// ---------------- BN stats over NHWC bf16 (c = idx & 63) ----------------
__global__ __launch_bounds__(256) void stats_nhwc(const unsigned short* __restrict__ h,
                                                  float* __restrict__ stats) {
  __shared__ float rs[256], rq[256];
  int tid = threadIdx.x;
  long base = (long)blockIdx.x * 32768 + tid;
  float s = 0.f, q = 0.f;
#pragma unroll 4
  for (int i = 0; i < 128; ++i) {
    float v = bfu2f(h[base + (long)i * 256]);
    s += v; q += v * v;
  }
  rs[tid] = s; rq[tid] = q;
  __syncthreads();
  if (tid < 64) {
    s = rs[tid] + rs[tid + 64] + rs[tid + 128] + rs[tid + 192];
    q = rq[tid] + rq[tid + 64] + rq[tid + 128] + rq[tid + 192];
    atomicAdd(&stats[tid], s);
    atomicAdd(&stats[64 + tid], q);
  }
}

// ---------------- finalize BN: stats -> per-channel scale/shift ----------------
__global__ void finalize_mode_kernel(const float* __restrict__ stats,
                                     float* __restrict__ params,
                                     const void* __restrict__ gamma,
                                     const void* __restrict__ beta,
                                     const void* __restrict__ xprobe) {
  __shared__ int sflag;
  int isf = block_detect_isf(xprobe, &sflag);
  int o = threadIdx.x;
  if (o < MK_CO) {
    const float M = (float)(MK_N * MK_H * MK_W);
    float mean = stats[o] / M;
    float var = stats[MK_CO + o] / M - mean * mean;
    float inv = rsqrtf(var + MK_EPS);
    float sc = rdv(gamma, o, isf) * inv;
    params[o] = sc;
    params[MK_CO + o] = rdv(beta, o, isf) - mean * sc;
  }
}

// ---------------- in-place BN+ReLU on NHWC bf16 (uint4 = 8 consecutive c) ----------------
__global__ __launch_bounds__(256) void bnrelu_nhwc(uint4* __restrict__ h,
                                                   const float* __restrict__ pr) {
  long i4 = (long)blockIdx.x * 256 + threadIdx.x;
  int c0 = ((int)i4 & 7) * 8;
  uint4 v = h[i4];
  unsigned* u = (unsigned*)&v;
#pragma unroll
  for (int k = 0; k < 4; ++k) {
    int c = c0 + 2 * k;
    float f0 = bfu2f((unsigned short)(u[k] & 0xFFFF));
    float f1 = bfu2f((unsigned short)(u[k] >> 16));
    f0 = fmaxf(fmaf(f0, pr[c], pr[64 + c]), 0.f);
    f1 = fmaxf(fmaf(f1, pr[c + 1], pr[64 + c + 1]), 0.f);
    unsigned lo = (unsigned)(unsigned short)f2bf_s(f0);
    unsigned hi = (unsigned)(unsigned short)f2bf_s(f1);
    u[k] = lo | (hi << 16);
  }
  h[i4] = v;
}

// ---------------- BN stats over fp32 NCHW: 64ch x 16 slices, float4 loads ----------------
__global__ __launch_bounds__(256) void stats_f32(const float* __restrict__ y,
                                                 float* __restrict__ stats) {
  __shared__ float rs[256], rq[256];
  const int o = blockIdx.x >> 4;    // channel
  const int sl = blockIdx.x & 15;   // slice of the 65536-px plane
  const int tid = threadIdx.x;
  float s = 0.f, q = 0.f;
#pragma unroll
  for (int n = 0; n < MK_N; ++n) {
    const float4* p = (const float4*)&y[(((long)(n * MK_CO + o)) << 16) + sl * 4096];
#pragma unroll
    for (int it = 0; it < 4; ++it) {
      float4 v = p[it * 256 + tid];
      s += v.x + v.y + v.z + v.w;
      q += v.x * v.x + v.y * v.y + v.z * v.z + v.w * v.w;
    }
  }
  rs[tid] = s; rq[tid] = q;
  __syncthreads();
  if (tid < 64) {
    s = rs[tid] + rs[tid + 64] + rs[tid + 128] + rs[tid + 192];
    q = rq[tid] + rq[tid + 64] + rq[tid + 128] + rq[tid + 192];
#pragma unroll
    for (int off = 32; off > 0; off >>= 1) {
      s += __shfl_down(s, off);
      q += __shfl_down(q, off);
    }
    if (tid == 0) {
      atomicAdd(&stats[o], s);
      atomicAdd(&stats[MK_CO + o], q);
    }
  }
}

// ---------------- in-place BN + ReLU, fp32 NCHW, float4 grid-stride ----------------
__global__ __launch_bounds__(256) void bn_relu_f32v(float4* __restrict__ y,
                                                    const float* __restrict__ params) {
  const long total = (long)MK_N * MK_CO * MK_H * MK_W / 4;  // 8388608
  for (long i = (long)blockIdx.x * 256 + threadIdx.x; i < total;
       i += (long)gridDim.x * 256) {
    int ch = (int)((i >> 14) & (MK_CO - 1));  // 16384 float4 per (n,ch) plane
    float sc = params[ch], sh = params[MK_CO + ch];
    float4 v = y[i];
    v.x = fmaxf(fmaf(v.x, sc, sh), 0.f);
    v.y = fmaxf(fmaf(v.y, sc, sh), 0.f);
    v.z = fmaxf(fmaf(v.z, sc, sh), 0.f);
    v.w = fmaxf(fmaf(v.w, sc, sh), 0.f);
    y[i] = v;
  }
}

extern "C" void kernel_launch(void* const* d_in, const int* in_sizes, int n_in,
                              void* d_out, int out_size, void* d_ws, size_t ws_size,
                              hipStream_t stream) {
  const void* x     = d_in[0];
  const void* t     = d_in[1];
  const void* w5_1  = d_in[2];
  const void* w3_1  = d_in[3];
  const void* w1_1  = d_in[4];
  const void* a3_1  = d_in[5];
  const void* a5_1  = d_in[6];
  const void* gw_1  = d_in[7];
  const void* gb_1  = d_in[8];
  const void* gamma_1 = d_in[9];
  const void* beta_1  = d_in[10];
  const void* w5_2  = d_in[11];
  const void* w3_2  = d_in[12];
  const void* w1_2  = d_in[13];
  const void* a3_2  = d_in[14];
  const void* a5_2  = d_in[15];
  const void* gw_2  = d_in[16];
  const void* gb_2  = d_in[17];
  const void* gamma_2 = d_in[18];
  const void* beta_2  = d_in[19];

  // Memory map (d_out = 128 MiB, ws = 64 MiB):
  //   d_out[0:32M)   : x_nhwc (dead after conv1; overwritten by conv2A output)
  //   d_out[32M]     : st1/pr1 (dead after bnrelu1)
  //   d_out[34M]     : P1 panels, 819200 B (dead after conv1)
  //   d_out[100M]    : P2 panels, 1638400 B (read by conv2A which writes [0,64M) only)
  //   d_out[0:128M)  : final fp32 NCHW output (conv2A writes n0-3, conv2B writes n4-7)
  //   ws[0:64M)      : h bf16 NHWC. After conv2A, ws[0:32M) (n0-3) is dead:
  //   ws[0]          : st2/pr2        ws[2M]: P2 copy for conv2B
  char* dob = (char*)d_out;
  short* x_nhwc = (short*)d_out;
  float* st1 = (float*)(dob + 33554432);
  float* pr1 = st1 + 128;
  short* P1  = (short*)(dob + 35651584);
  short* P2  = (short*)(dob + 104857600);
  float* out = (float*)d_out;

  short* h   = (short*)d_ws;
  float* st2 = (float*)d_ws;
  float* pr2 = st2 + 128;
  short* P2c = (short*)d_ws + 1048576;  // ws + 2 MiB

  // ---- panels (both layers depend only on t + weight inputs) ----
  make_panels<32><<<dim3(25, 8), 256, 0, stream>>>(t, gw_1, gb_1, w5_1, w3_1, w1_1, a3_1, a5_1, P1, x);
  make_panels<64><<<dim3(25, 8), 256, 0, stream>>>(t, gw_2, gb_2, w5_2, w3_2, w1_2, a3_2, a5_2, P2, x);

  // ---- layer 1 ----
  x_to_nhwc<<<dim3(4, 256, 8), 256, 0, stream>>>(x, x_nhwc, x);
  zero128_kernel<<<1, 128, 0, stream>>>(st1);
  conv_mfma<32, false><<<dim3(4, 64, 8), 256, 0, stream>>>(x_nhwc, P1, h, 0);
  stats_nhwc<<<1024, 256, 0, stream>>>((const unsigned short*)h, st1);
  finalize_mode_kernel<<<1, 64, 0, stream>>>(st1, pr1, gamma_1, beta_1, x);
  bnrelu_nhwc<<<16384, 256, 0, stream>>>((uint4*)h, pr1);

  // ---- layer 2 (split so panels are never read after being overwritten) ----
  conv_mfma<64, true><<<dim3(4, 64, 4), 256, 0, stream>>>(h, P2, out, 0);
  copy16<<<400, 256, 0, stream>>>((const short8*)P2, (short8*)P2c, 102400);
  conv_mfma<64, true><<<dim3(4, 64, 4), 256, 0, stream>>>(h, P2c, out, 4);
  zero128_kernel<<<1, 128, 0, stream>>>(st2);
  stats_f32<<<1024, 256, 0, stream>>>(out, st2);
  finalize_mode_kernel<<<1, 64, 0, stream>>>(st2, pr2, gamma_2, beta_2, x);
  bn_relu_f32v<<<2048, 256, 0, stream>>>((float4*)out, pr2);
}

// Round 4
// 567.528 us; speedup vs baseline: 5.2297x; 1.0875x over previous
//
#include <hip/hip_runtime.h>
#include <hip/hip_bf16.h>

#define MK_N 8
#define MK_T 8
#define MK_H 256
#define MK_W 256
#define MK_CO 64
#define MK_EPS 1e-5f

typedef __attribute__((ext_vector_type(8))) short short8;
typedef __attribute__((ext_vector_type(4))) short short4v;
typedef __attribute__((ext_vector_type(4))) float f32x4;

// read element idx from p, which is fp32 (isf32=1) or bf16 (isf32=0)
__device__ __forceinline__ float rdv(const void* p, long idx, int isf32) {
  return isf32 ? ((const float*)p)[idx]
               : __bfloat162float(((const __hip_bfloat16*)p)[idx]);
}

__device__ __forceinline__ short f2bf_s(float f) {
  __hip_bfloat16 b = __float2bfloat16(f);
  union { __hip_bfloat16 b; short s; } u; u.b = b; return u.s;
}
__device__ __forceinline__ float bfu2f(unsigned short s) {
  return __uint_as_float((unsigned)s << 16);
}

// Inline dtype probe on pristine x: bf16 -> sane exponents; fp32 -> ~45% insane.
__device__ __forceinline__ int block_detect_isf(const void* xprobe, int* sflag) {
  if (threadIdx.x < 64) {
    const unsigned short* u16 = (const unsigned short*)xprobe;
    int insane = 0;
#pragma unroll
    for (int j = 0; j < 4; ++j) {
      unsigned short u = u16[threadIdx.x * 4 + j];
      int e = (u >> 7) & 0xFF;
      bool zero = (u & 0x7FFF) == 0;
      if (!(zero || (e >= 0x60 && e <= 0x85))) insane++;
    }
#pragma unroll
    for (int off = 32; off > 0; off >>= 1) insane += __shfl_down(insane, off);
    if (threadIdx.x == 0) *sflag = (insane > 32) ? 1 : 0;
  }
  __syncthreads();
  return *sflag;
}

__global__ void zero128_kernel(float* __restrict__ p) { p[threadIdx.x] = 0.f; }

// ---------------- x (NCHW, fp32|bf16) -> NHWC bf16 ----------------
__global__ __launch_bounds__(256) void x_to_nhwc(const void* __restrict__ x,
                                                 short* __restrict__ xo,
                                                 const void* __restrict__ xprobe) {
  __shared__ float xl[32 * 65];
  __shared__ int sflag;
  int isf = block_detect_isf(xprobe, &sflag);
  int n = blockIdx.z, y = blockIdx.y, x0 = blockIdx.x * 64;
  int tid = threadIdx.x;
  {
    int c = tid >> 3, ch = tid & 7;
    long base = ((long)(n * 32 + c) * 256 + y) * 256 + x0 + ch * 8;
#pragma unroll
    for (int j = 0; j < 8; ++j) xl[c * 65 + ch * 8 + j] = rdv(x, base + j, isf);
  }
  __syncthreads();
  {
    int xi = tid >> 2, cc = tid & 3;
    short8 v;
#pragma unroll
    for (int j = 0; j < 8; ++j) v[j] = f2bf_s(xl[(cc * 8 + j) * 65 + xi]);
    *(short8*)&xo[(((long)(n * 256 + y) * 256) + x0 + xi) * 32 + cc * 8] = v;
  }
}

// ---------------- panel precompute: gates + mixed weights, once per (n,s) ----------------
// Panel layout: [n][hc][s][o=64][c=32] bf16  (exactly the MFMA A-fragment order)
template <int CI>
__global__ __launch_bounds__(256) void make_panels(
    const void* __restrict__ t, const void* __restrict__ gw, const void* __restrict__ gb,
    const void* __restrict__ w5, const void* __restrict__ w3, const void* __restrict__ w1,
    const void* __restrict__ a3, const void* __restrict__ a5,
    short* __restrict__ pan, const void* __restrict__ xprobe) {
  __shared__ float slog[320], sgate[320];
  __shared__ int sflag;
  const int s = blockIdx.x, n = blockIdx.y;
  const int tid = threadIdx.x;
  const int isf = block_detect_isf(xprobe, &sflag);

  for (int eo = tid; eo < 320; eo += 256) {
    int e = eo >> 6, o = eo & 63;
    long row = e * 64 + o;
    float sacc = rdv(gb, row, isf);
#pragma unroll
    for (int k = 0; k < MK_T; ++k)
      sacc += rdv(t, n * MK_T + k, isf) * rdv(gw, row * MK_T + k, isf);
    slog[e * 64 + o] = sacc;
  }
  __syncthreads();
  if (tid < 64) {
    float m = slog[tid];
#pragma unroll
    for (int e = 1; e < 5; ++e) m = fmaxf(m, slog[e * 64 + tid]);
    float tmp[5], sum = 0.f;
#pragma unroll
    for (int e = 0; e < 5; ++e) { tmp[e] = expf(slog[e * 64 + tid] - m); sum += tmp[e]; }
    float inv = 1.f / sum;
#pragma unroll
    for (int e = 0; e < 5; ++e) sgate[tid * 5 + e] = tmp[e] * inv;
  }
  __syncthreads();

  const int mo = tid >> 2, gq = tid & 3;
  float ge[5];
#pragma unroll
  for (int e = 0; e < 5; ++e) ge[e] = sgate[mo * 5 + e];

  const int ky = s / 5, kx = s - ky * 5;
  const bool in3 = (ky >= 1 && ky <= 3 && kx >= 1 && kx <= 3);
  const int HC = CI / 32;
#pragma unroll
  for (int hc = 0; hc < HC; ++hc) {
    short8 pk;
#pragma unroll
    for (int j = 0; j < 8; ++j) {
      long oc = (long)mo * CI + hc * 32 + gq * 8 + j;
      float pa3 = rdv(a3, oc, isf) * (1.f / 27.f);
      float pa5 = rdv(a5, oc, isf) * (1.f / 125.f);
      float v = ge[0] * rdv(w5, oc * 25 + s, isf);
      if (in3) {
        v += ge[1] * rdv(w3, oc * 9 + (ky - 1) * 3 + (kx - 1), isf);
        v += ge[3] * pa3;
      }
      if (s == 12) v += ge[2] * rdv(w1, oc, isf);
      v += ge[4] * pa5;
      pk[j] = f2bf_s(v);
    }
    *(short8*)&pan[((((long)n * HC + hc) * 25 + s) * 64 + mo) * 32 + gq * 8] = pk;
  }
}

// ---------------- trivial 16B copy ----------------
__global__ __launch_bounds__(256) void copy16(const short8* __restrict__ src,
                                              short8* __restrict__ dst, int n16) {
  int i = blockIdx.x * 256 + threadIdx.x;
  if (i < n16) dst[i] = src[i];
}

// ---------------- MFMA implicit-GEMM conv ----------------
// Block: 256 thr (4 waves). Tile: [CO=64] x [4 rows] x [64 cols], sample n.
// 25 shifted GEMMs; A from precomputed global panel (L2-hot, coalesced 1KB/wave),
// B from LDS xt. Explicit 2-deep fragment prefetch + setprio around MFMA cluster.
// xt pad = 36 shorts (72B rows, gcd(18,32)=2 -> even bank spread), 8B-aligned
// short4v accesses.
// BNIN: apply per-channel scale/shift + ReLU (layer-1 BN) while staging input.
template <int CI, bool FINAL, bool BNIN>
__global__ __launch_bounds__(256, 3) void conv_mfma(
    const short* __restrict__ xsrc,   // NHWC bf16 [8][256][256][CI]
    const short* __restrict__ pan,    // [n][hc][s][64][32] bf16
    void* __restrict__ outp,          // FINAL ? float* NCHW : short* NHWC bf16
    int nbase,
    const float* __restrict__ pr)     // BNIN: [64] scale, [64] shift
{
  __shared__ short xt[8 * 68 * 36];   // 39168 B
  __shared__ float spr[128];

  const int tid = threadIdx.x;
  const int x0 = blockIdx.x * 64;
  const int r0 = blockIdx.y * 4;
  const int n = blockIdx.z + nbase;

  if (BNIN) {
    if (tid < 128) spr[tid] = pr[tid];
  }

  const int lane = tid & 63, w = tid >> 6;
  const int quad = lane >> 4, l15 = lane & 15;

  int baseB[4];
#pragma unroll
  for (int p = 0; p < 4; ++p)
    baseB[p] = (w * 68 + p * 16 + l15) * 36 + quad * 8;
  int aoff[4];
#pragma unroll
  for (int ot = 0; ot < 4; ++ot)
    aoff[ot] = (ot * 16 + l15) * 32 + quad * 8;

  f32x4 acc[4][4];
#pragma unroll
  for (int ot = 0; ot < 4; ++ot)
#pragma unroll
    for (int p = 0; p < 4; ++p) acc[ot][p] = f32x4{0.f, 0.f, 0.f, 0.f};

  const int HC = CI / 32;
#pragma unroll 1
  for (int hc = 0; hc < HC; ++hc) {
    const int cbase = hc * 32;
    __syncthreads();  // xt WAR (hc>0) + spr visibility

    // ---- stage x tile (8 rows x 68 cols x 32 ch), optional fused BN+ReLU ----
    for (int idx = tid; idx < 8 * 68 * 4; idx += 256) {
      int r = idx / (68 * 4);
      int rem = idx - r * (68 * 4);
      int col = rem >> 2, ch = rem & 3;
      int gy = r0 - 2 + r, gx = x0 - 2 + col;
      short8 v = short8{0, 0, 0, 0, 0, 0, 0, 0};
      if ((unsigned)gy < 256u && (unsigned)gx < 256u) {
        v = *(const short8*)&xsrc[(((long)(n * 256 + gy) * 256) + gx) * CI + cbase + ch * 8];
        if (BNIN) {
#pragma unroll
          for (int j = 0; j < 8; ++j) {
            int c = cbase + ch * 8 + j;
            float f = bfu2f((unsigned short)v[j]);
            v[j] = f2bf_s(fmaxf(fmaf(f, spr[c], spr[64 + c]), 0.f));
          }
        }
      }
      short4v lo, hi;
#pragma unroll
      for (int j = 0; j < 4; ++j) { lo[j] = v[j]; hi[j] = v[4 + j]; }
      int sb = (r * 68 + col) * 36 + ch * 8;
      *(short4v*)&xt[sb] = lo;
      *(short4v*)&xt[sb + 4] = hi;
    }
    __syncthreads();

    const short* ps = pan + (((long)n * HC + hc) * 25) * 2048;

    short8 afc[4], bfc[4];
    // preload s = 0
#pragma unroll
    for (int ot = 0; ot < 4; ++ot) afc[ot] = *(const short8*)&ps[aoff[ot]];
#pragma unroll
    for (int p = 0; p < 4; ++p) {
      short4v lo = *(const short4v*)&xt[baseB[p] + (0 * 68 + 0) * 36];
      short4v hi = *(const short4v*)&xt[baseB[p] + (0 * 68 + 0) * 36 + 4];
      short8 b;
#pragma unroll
      for (int j = 0; j < 4; ++j) { b[j] = lo[j]; b[4 + j] = hi[j]; }
      bfc[p] = b;
    }

#pragma unroll
    for (int s = 0; s < 25; ++s) {
      short8 afn[4], bfn[4];
      if (s < 24) {
        const int sn = s + 1;
        const int kyn = sn / 5, kxn = sn - kyn * 5;
        const int koffn = (kyn * 68 + kxn) * 36;
#pragma unroll
        for (int ot = 0; ot < 4; ++ot) afn[ot] = *(const short8*)&ps[sn * 2048 + aoff[ot]];
#pragma unroll
        for (int p = 0; p < 4; ++p) {
          short4v lo = *(const short4v*)&xt[baseB[p] + koffn];
          short4v hi = *(const short4v*)&xt[baseB[p] + koffn + 4];
          short8 b;
#pragma unroll
          for (int j = 0; j < 4; ++j) { b[j] = lo[j]; b[4 + j] = hi[j]; }
          bfn[p] = b;
        }
      }
      __builtin_amdgcn_s_setprio(1);
#pragma unroll
      for (int ot = 0; ot < 4; ++ot)
#pragma unroll
        for (int p = 0; p < 4; ++p)
          acc[ot][p] = __builtin_amdgcn_mfma_f32_16x16x32_bf16(afc[ot], bfc[p], acc[ot][p], 0, 0, 0);
      __builtin_amdgcn_s_setprio(0);
      if (s < 24) {
#pragma unroll
        for (int i = 0; i < 4; ++i) { afc[i] = afn[i]; bfc[i] = bfn[i]; }
      }
    }
  }

  if (FINAL) {
    // fp32 NCHW direct stores
    float* out = (float*)outp;
#pragma unroll
    for (int ot = 0; ot < 4; ++ot)
#pragma unroll
      for (int p = 0; p < 4; ++p)
#pragma unroll
        for (int r = 0; r < 4; ++r) {
          int oo = ot * 16 + quad * 4 + r;
          long off = ((long)(n * 64 + oo) << 16) + (r0 + w) * 256 + x0 + p * 16 + l15;
          out[off] = acc[ot][p][r];
        }
  } else {
    __syncthreads();  // all xt reads done before aliasing
    // bf16 NHWC via LDS bounce (alias xt; need 4*64*72 = 18432 shorts <= 19584)
    short* cbuf = xt;
#pragma unroll
    for (int ot = 0; ot < 4; ++ot)
#pragma unroll
      for (int p = 0; p < 4; ++p) {
        short4v pk;
#pragma unroll
        for (int r = 0; r < 4; ++r) pk[r] = f2bf_s(acc[ot][p][r]);
        *(short4v*)&cbuf[(w * 64 + p * 16 + l15) * 72 + ot * 16 + quad * 4] = pk;
      }
    __syncthreads();
    short* hout = (short*)outp;
    for (int idx = tid; idx < 2048; idx += 256) {
      int w2 = idx >> 9, rem = idx & 511;
      int px = rem >> 3, ch = rem & 7;
      short8 v = *(const short8*)&cbuf[(w2 * 64 + px) * 72 + ch * 8];
      *(short8*)&hout[(((long)(n * 256 + r0 + w2) * 256) + x0 + px) * 64 + ch * 8] = v;
    }
  }
}

// ---------------- BN stats over NHWC bf16 (c = idx & 63) ----------------
__global__ __launch_bounds__(256) void stats_nhwc(const unsigned short* __restrict__ h,
                                                  float* __restrict__ stats) {
  __shared__ float rs[256], rq[256];
  int tid = threadIdx.x;
  long base = (long)blockIdx.x * 32768 + tid;
  float s = 0.f, q = 0.f;
#pragma unroll 4
  for (int i = 0; i < 128; ++i) {
    float v = bfu2f(h[base + (long)i * 256]);
    s += v; q += v * v;
  }
  rs[tid] = s; rq[tid] = q;
  __syncthreads();
  if (tid < 64) {
    s = rs[tid] + rs[tid + 64] + rs[tid + 128] + rs[tid + 192];
    q = rq[tid] + rq[tid + 64] + rq[tid + 128] + rq[tid + 192];
    atomicAdd(&stats[tid], s);
    atomicAdd(&stats[64 + tid], q);
  }
}

// ---------------- finalize BN: stats -> per-channel scale/shift ----------------
__global__ void finalize_mode_kernel(const float* __restrict__ stats,
                                     float* __restrict__ params,
                                     const void* __restrict__ gamma,
                                     const void* __restrict__ beta,
                                     const void* __restrict__ xprobe) {
  __shared__ int sflag;
  int isf = block_detect_isf(xprobe, &sflag);
  int o = threadIdx.x;
  if (o < MK_CO) {
    const float M = (float)(MK_N * MK_H * MK_W);
    float mean = stats[o] / M;
    float var = stats[MK_CO + o] / M - mean * mean;
    float inv = rsqrtf(var + MK_EPS);
    float sc = rdv(gamma, o, isf) * inv;
    params[o] = sc;
    params[MK_CO + o] = rdv(beta, o, isf) - mean * sc;
  }
}

// ---------------- BN stats over fp32 NCHW: 64ch x 16 slices, float4 loads ----------------
__global__ __launch_bounds__(256) void stats_f32(const float* __restrict__ y,
                                                 float* __restrict__ stats) {
  __shared__ float rs[256], rq[256];
  const int o = blockIdx.x >> 4;    // channel
  const int sl = blockIdx.x & 15;   // slice of the 65536-px plane
  const int tid = threadIdx.x;
  float s = 0.f, q = 0.f;
#pragma unroll
  for (int n = 0; n < MK_N; ++n) {
    const float4* p = (const float4*)&y[(((long)(n * MK_CO + o)) << 16) + sl * 4096];
#pragma unroll
    for (int it = 0; it < 4; ++it) {
      float4 v = p[it * 256 + tid];
      s += v.x + v.y + v.z + v.w;
      q += v.x * v.x + v.y * v.y + v.z * v.z + v.w * v.w;
    }
  }
  rs[tid] = s; rq[tid] = q;
  __syncthreads();
  if (tid < 64) {
    s = rs[tid] + rs[tid + 64] + rs[tid + 128] + rs[tid + 192];
    q = rq[tid] + rq[tid + 64] + rq[tid + 128] + rq[tid + 192];
#pragma unroll
    for (int off = 32; off > 0; off >>= 1) {
      s += __shfl_down(s, off);
      q += __shfl_down(q, off);
    }
    if (tid == 0) {
      atomicAdd(&stats[o], s);
      atomicAdd(&stats[MK_CO + o], q);
    }
  }
}

// ---------------- in-place BN + ReLU, fp32 NCHW, float4 grid-stride ----------------
__global__ __launch_bounds__(256) void bn_relu_f32v(float4* __restrict__ y,
                                                    const float* __restrict__ params) {
  const long total = (long)MK_N * MK_CO * MK_H * MK_W / 4;  // 8388608
  for (long i = (long)blockIdx.x * 256 + threadIdx.x; i < total;
       i += (long)gridDim.x * 256) {
    int ch = (int)((i >> 14) & (MK_CO - 1));  // 16384 float4 per (n,ch) plane
    float sc = params[ch], sh = params[MK_CO + ch];
    float4 v = y[i];
    v.x = fmaxf(fmaf(v.x, sc, sh), 0.f);
    v.y = fmaxf(fmaf(v.y, sc, sh), 0.f);
    v.z = fmaxf(fmaf(v.z, sc, sh), 0.f);
    v.w = fmaxf(fmaf(v.w, sc, sh), 0.f);
    y[i] = v;
  }
}

extern "C" void kernel_launch(void* const* d_in, const int* in_sizes, int n_in,
                              void* d_out, int out_size, void* d_ws, size_t ws_size,
                              hipStream_t stream) {
  const void* x     = d_in[0];
  const void* t     = d_in[1];
  const void* w5_1  = d_in[2];
  const void* w3_1  = d_in[3];
  const void* w1_1  = d_in[4];
  const void* a3_1  = d_in[5];
  const void* a5_1  = d_in[6];
  const void* gw_1  = d_in[7];
  const void* gb_1  = d_in[8];
  const void* gamma_1 = d_in[9];
  const void* beta_1  = d_in[10];
  const void* w5_2  = d_in[11];
  const void* w3_2  = d_in[12];
  const void* w1_2  = d_in[13];
  const void* a3_2  = d_in[14];
  const void* a5_2  = d_in[15];
  const void* gw_2  = d_in[16];
  const void* gb_2  = d_in[17];
  const void* gamma_2 = d_in[18];
  const void* beta_2  = d_in[19];

  // Memory map (d_out = 128 MiB, ws = 64 MiB):
  //   d_out[0:32M)     : x_nhwc (dead after conv1; overwritten by conv2A output)
  //   d_out[32M]       : st1 (dead after finalize1)
  //   d_out[34M]       : P1 panels, 819200 B (dead after conv1)
  //   d_out[100M]      : P2 panels, 1638400 B  + pr1_hi (512 B) right after
  //                      (read by conv2A which writes [0,64M) only)
  //   d_out[0:128M)    : final fp32 NCHW output (conv2A n0-3, conv2B n4-7)
  //   ws[0:64M)        : h bf16 NHWC. After conv2A, ws[0:32M) (n0-3) is dead:
  //   ws[0]            : st2/pr2        ws[2M] : P2+pr1 copy for conv2B
  char* dob = (char*)d_out;
  short* x_nhwc = (short*)d_out;
  float* st1 = (float*)(dob + 33554432);
  short* P1  = (short*)(dob + 35651584);
  short* P2  = (short*)(dob + 104857600);
  float* pr1_hi = (float*)(dob + 104857600 + 1638400);
  float* out = (float*)d_out;

  short* h   = (short*)d_ws;
  float* st2 = (float*)d_ws;
  float* pr2 = st2 + 128;
  short* P2c = (short*)d_ws + 1048576;  // ws + 2 MiB
  float* pr1c = (float*)((char*)P2c + 1638400);

  // ---- panels (both layers depend only on t + weight inputs) ----
  make_panels<32><<<dim3(25, 8), 256, 0, stream>>>(t, gw_1, gb_1, w5_1, w3_1, w1_1, a3_1, a5_1, P1, x);
  make_panels<64><<<dim3(25, 8), 256, 0, stream>>>(t, gw_2, gb_2, w5_2, w3_2, w1_2, a3_2, a5_2, P2, x);

  // ---- layer 1 ----
  x_to_nhwc<<<dim3(4, 256, 8), 256, 0, stream>>>(x, x_nhwc, x);
  zero128_kernel<<<1, 128, 0, stream>>>(st1);
  conv_mfma<32, false, false><<<dim3(4, 64, 8), 256, 0, stream>>>(x_nhwc, P1, h, 0, nullptr);
  stats_nhwc<<<1024, 256, 0, stream>>>((const unsigned short*)h, st1);
  finalize_mode_kernel<<<1, 64, 0, stream>>>(st1, pr1_hi, gamma_1, beta_1, x);

  // ---- layer 2 (BN+ReLU of layer 1 fused into staging; split so panels/pr are
  //      never read after being overwritten) ----
  conv_mfma<64, true, true><<<dim3(4, 64, 4), 256, 0, stream>>>(h, P2, out, 0, pr1_hi);
  copy16<<<401, 256, 0, stream>>>((const short8*)P2, (short8*)P2c, 102432);  // P2 + pr1
  conv_mfma<64, true, true><<<dim3(4, 64, 4), 256, 0, stream>>>(h, P2c, out, 4, pr1c);
  zero128_kernel<<<1, 128, 0, stream>>>(st2);
  stats_f32<<<1024, 256, 0, stream>>>(out, st2);
  finalize_mode_kernel<<<1, 64, 0, stream>>>(st2, pr2, gamma_2, beta_2, x);
  bn_relu_f32v<<<2048, 256, 0, stream>>>((float4*)out, pr2);
}

// Round 6
// 468.973 us; speedup vs baseline: 6.3288x; 1.2102x over previous
//
#include <hip/hip_runtime.h>
#include <hip/hip_bf16.h>

#define MK_N 8
#define MK_T 8
#define MK_H 256
#define MK_W 256
#define MK_CO 64
#define MK_EPS 1e-5f

typedef __attribute__((ext_vector_type(8))) short short8;
typedef __attribute__((ext_vector_type(4))) short short4v;
typedef __attribute__((ext_vector_type(4))) float f32x4;

// read element idx from p, which is fp32 (isf32=1) or bf16 (isf32=0)
__device__ __forceinline__ float rdv(const void* p, long idx, int isf32) {
  return isf32 ? ((const float*)p)[idx]
               : __bfloat162float(((const __hip_bfloat16*)p)[idx]);
}

__device__ __forceinline__ short f2bf_s(float f) {
  __hip_bfloat16 b = __float2bfloat16(f);
  union { __hip_bfloat16 b; short s; } u; u.b = b; return u.s;
}
__device__ __forceinline__ float bfu2f(unsigned short s) {
  return __uint_as_float((unsigned)s << 16);
}

// Inline dtype probe on pristine x: bf16 -> sane exponents; fp32 -> ~45% insane.
__device__ __forceinline__ int block_detect_isf(const void* xprobe, int* sflag) {
  if (threadIdx.x < 64) {
    const unsigned short* u16 = (const unsigned short*)xprobe;
    int insane = 0;
#pragma unroll
    for (int j = 0; j < 4; ++j) {
      unsigned short u = u16[threadIdx.x * 4 + j];
      int e = (u >> 7) & 0xFF;
      bool zero = (u & 0x7FFF) == 0;
      if (!(zero || (e >= 0x60 && e <= 0x85))) insane++;
    }
#pragma unroll
    for (int off = 32; off > 0; off >>= 1) insane += __shfl_down(insane, off);
    if (threadIdx.x == 0) *sflag = (insane > 32) ? 1 : 0;
  }
  __syncthreads();
  return *sflag;
}

__global__ void zero128_kernel(float* __restrict__ p) { p[threadIdx.x] = 0.f; }

// ---------------- x (NCHW, fp32|bf16) -> NHWC bf16 ----------------
__global__ __launch_bounds__(256) void x_to_nhwc(const void* __restrict__ x,
                                                 short* __restrict__ xo,
                                                 const void* __restrict__ xprobe) {
  __shared__ float xl[32 * 65];
  __shared__ int sflag;
  int isf = block_detect_isf(xprobe, &sflag);
  int n = blockIdx.z, y = blockIdx.y, x0 = blockIdx.x * 64;
  int tid = threadIdx.x;
  {
    int c = tid >> 3, ch = tid & 7;
    long base = ((long)(n * 32 + c) * 256 + y) * 256 + x0 + ch * 8;
#pragma unroll
    for (int j = 0; j < 8; ++j) xl[c * 65 + ch * 8 + j] = rdv(x, base + j, isf);
  }
  __syncthreads();
  {
    int xi = tid >> 2, cc = tid & 3;
    short8 v;
#pragma unroll
    for (int j = 0; j < 8; ++j) v[j] = f2bf_s(xl[(cc * 8 + j) * 65 + xi]);
    *(short8*)&xo[(((long)(n * 256 + y) * 256) + x0 + xi) * 32 + cc * 8] = v;
  }
}

// ---------------- panel precompute: gates + mixed weights, once per (n,s) ----------------
// Panel layout: [n][hc][s][o=64][c=32] bf16  (exactly the MFMA A-fragment order)
template <int CI>
__global__ __launch_bounds__(256) void make_panels(
    const void* __restrict__ t, const void* __restrict__ gw, const void* __restrict__ gb,
    const void* __restrict__ w5, const void* __restrict__ w3, const void* __restrict__ w1,
    const void* __restrict__ a3, const void* __restrict__ a5,
    short* __restrict__ pan, const void* __restrict__ xprobe) {
  __shared__ float slog[320], sgate[320];
  __shared__ int sflag;
  const int s = blockIdx.x, n = blockIdx.y;
  const int tid = threadIdx.x;
  const int isf = block_detect_isf(xprobe, &sflag);

  for (int eo = tid; eo < 320; eo += 256) {
    int e = eo >> 6, o = eo & 63;
    long row = e * 64 + o;
    float sacc = rdv(gb, row, isf);
#pragma unroll
    for (int k = 0; k < MK_T; ++k)
      sacc += rdv(t, n * MK_T + k, isf) * rdv(gw, row * MK_T + k, isf);
    slog[e * 64 + o] = sacc;
  }
  __syncthreads();
  if (tid < 64) {
    float m = slog[tid];
#pragma unroll
    for (int e = 1; e < 5; ++e) m = fmaxf(m, slog[e * 64 + tid]);
    float tmp[5], sum = 0.f;
#pragma unroll
    for (int e = 0; e < 5; ++e) { tmp[e] = expf(slog[e * 64 + tid] - m); sum += tmp[e]; }
    float inv = 1.f / sum;
#pragma unroll
    for (int e = 0; e < 5; ++e) sgate[tid * 5 + e] = tmp[e] * inv;
  }
  __syncthreads();

  const int mo = tid >> 2, gq = tid & 3;
  float ge[5];
#pragma unroll
  for (int e = 0; e < 5; ++e) ge[e] = sgate[mo * 5 + e];

  const int ky = s / 5, kx = s - ky * 5;
  const bool in3 = (ky >= 1 && ky <= 3 && kx >= 1 && kx <= 3);
  const int HC = CI / 32;
#pragma unroll
  for (int hc = 0; hc < HC; ++hc) {
    short8 pk;
#pragma unroll
    for (int j = 0; j < 8; ++j) {
      long oc = (long)mo * CI + hc * 32 + gq * 8 + j;
      float pa3 = rdv(a3, oc, isf) * (1.f / 27.f);
      float pa5 = rdv(a5, oc, isf) * (1.f / 125.f);
      float v = ge[0] * rdv(w5, oc * 25 + s, isf);
      if (in3) {
        v += ge[1] * rdv(w3, oc * 9 + (ky - 1) * 3 + (kx - 1), isf);
        v += ge[3] * pa3;
      }
      if (s == 12) v += ge[2] * rdv(w1, oc, isf);
      v += ge[4] * pa5;
      pk[j] = f2bf_s(v);
    }
    *(short8*)&pan[((((long)n * HC + hc) * 25 + s) * 64 + mo) * 32 + gq * 8] = pk;
  }
}

// ---------------- trivial 16B copy ----------------
__global__ __launch_bounds__(256) void copy16(const short8* __restrict__ src,
                                              short8* __restrict__ dst, int n16) {
  int i = blockIdx.x * 256 + threadIdx.x;
  if (i < n16) dst[i] = src[i];
}

// ---------------- partials reduce: st[ch] += sum_k part[ch*nb + k] ----------------
__global__ __launch_bounds__(256) void reduce_partials(const float* __restrict__ part,
                                                       float* __restrict__ st, int nb) {
  __shared__ float r[256];
  const int ch = blockIdx.x;  // 0..127
  float s = 0.f;
  for (int k = threadIdx.x; k < nb; k += 256) s += part[(long)ch * nb + k];
  r[threadIdx.x] = s;
  __syncthreads();
  if (threadIdx.x < 64) {
    s = r[threadIdx.x] + r[threadIdx.x + 64] + r[threadIdx.x + 128] + r[threadIdx.x + 192];
#pragma unroll
    for (int off = 32; off > 0; off >>= 1) s += __shfl_down(s, off);
    if (threadIdx.x == 0) atomicAdd(&st[ch], s);
  }
}

// ---------------- MFMA implicit-GEMM conv, 8-row blocks ----------------
// Block: 256 thr (4 waves). Tile: [CO=64] x [8 rows] x [64 cols], sample n.
// Each wave owns rows {w, w+4}: 32 MFMAs per s-iter (~155cy window) vs 4 global
// A-loads -> latency hidden by 2 waves/SIMD + 1-deep A prefetch.
// Fused epilogue: per-block per-channel BN partial sums (from fp32 acc).
// BNIN: apply layer-1 BN scale/shift + ReLU while staging input.
template <int CI, bool FINAL, bool BNIN>
__global__ __launch_bounds__(256, 2) void conv_mfma(
    const short* __restrict__ xsrc,   // NHWC bf16 [8][256][256][CI]
    const short* __restrict__ pan,    // [n][hc][s][64][32] bf16
    void* __restrict__ outp,          // FINAL ? float* NCHW : short* NHWC bf16
    int nbase,
    const float* __restrict__ pr,     // BNIN: [64] scale, [64] shift
    float* __restrict__ partials,     // [128][NB]
    int NB)
{
  // xt: 12 rows x 68 cols x 36-short pad = 29376 shorts.
  // non-FINAL also needs cbuf 8*64*72=36864 + slds 1024 shorts (aliased).
  constexpr int XT_SH = FINAL ? 29376 : 37888;
  __shared__ short xt[XT_SH];
  __shared__ float spr[128];

  const int tid = threadIdx.x;
  const int x0 = blockIdx.x * 64;
  const int r0 = blockIdx.y * 8;
  const int n = blockIdx.z + nbase;
  const int bid = (blockIdx.z * gridDim.y + blockIdx.y) * gridDim.x + blockIdx.x;

  if (BNIN) {
    if (tid < 128) spr[tid] = pr[tid];
  }

  const int lane = tid & 63, w = tid >> 6;
  const int quad = lane >> 4, l15 = lane & 15;

  int baseB[2][4];
#pragma unroll
  for (int rr = 0; rr < 2; ++rr)
#pragma unroll
    for (int p = 0; p < 4; ++p)
      baseB[rr][p] = ((w + rr * 4) * 68 + p * 16 + l15) * 36 + quad * 8;
  int aoff[4];
#pragma unroll
  for (int ot = 0; ot < 4; ++ot)
    aoff[ot] = (ot * 16 + l15) * 32 + quad * 8;

  f32x4 acc[2][4][4];
#pragma unroll
  for (int rr = 0; rr < 2; ++rr)
#pragma unroll
    for (int ot = 0; ot < 4; ++ot)
#pragma unroll
      for (int p = 0; p < 4; ++p) acc[rr][ot][p] = f32x4{0.f, 0.f, 0.f, 0.f};

  const int HC = CI / 32;
#pragma unroll 1
  for (int hc = 0; hc < HC; ++hc) {
    const int cbase = hc * 32;
    __syncthreads();  // xt WAR (hc>0) + spr visibility

    // ---- stage x tile (12 rows x 68 cols x 32 ch), optional fused BN+ReLU ----
    for (int idx = tid; idx < 12 * 68 * 4; idx += 256) {
      int r = idx / (68 * 4);
      int rem = idx - r * (68 * 4);
      int col = rem >> 2, ch = rem & 3;
      int gy = r0 - 2 + r, gx = x0 - 2 + col;
      short8 v = short8{0, 0, 0, 0, 0, 0, 0, 0};
      if ((unsigned)gy < 256u && (unsigned)gx < 256u) {
        v = *(const short8*)&xsrc[(((long)(n * 256 + gy) * 256) + gx) * CI + cbase + ch * 8];
        if (BNIN) {
#pragma unroll
          for (int j = 0; j < 8; ++j) {
            int c = cbase + ch * 8 + j;
            float f = bfu2f((unsigned short)v[j]);
            v[j] = f2bf_s(fmaxf(fmaf(f, spr[c], spr[64 + c]), 0.f));
          }
        }
      }
      short4v lo, hi;
#pragma unroll
      for (int j = 0; j < 4; ++j) { lo[j] = v[j]; hi[j] = v[4 + j]; }
      int sb = (r * 68 + col) * 36 + ch * 8;
      *(short4v*)&xt[sb] = lo;
      *(short4v*)&xt[sb + 4] = hi;
    }
    __syncthreads();

    const short* ps = pan + (((long)n * HC + hc) * 25) * 2048;

    // preload s = 0 A-fragments
    short8 afc[4];
#pragma unroll
    for (int ot = 0; ot < 4; ++ot) afc[ot] = *(const short8*)&ps[aoff[ot]];

#pragma unroll
    for (int s = 0; s < 25; ++s) {
      const int ky = s / 5, kx = s - ky * 5;
      const int koff = (ky * 68 + kx) * 36;
      // prefetch next A (global, L2) so latency hides under B-loads + MFMAs
      short8 afn[4];
      if (s < 24) {
#pragma unroll
        for (int ot = 0; ot < 4; ++ot)
          afn[ot] = *(const short8*)&ps[(s + 1) * 2048 + aoff[ot]];
      }
      short8 bf[2][4];
#pragma unroll
      for (int rr = 0; rr < 2; ++rr)
#pragma unroll
        for (int p = 0; p < 4; ++p) {
          short4v lo = *(const short4v*)&xt[baseB[rr][p] + koff];
          short4v hi = *(const short4v*)&xt[baseB[rr][p] + koff + 4];
          short8 b;
#pragma unroll
          for (int j = 0; j < 4; ++j) { b[j] = lo[j]; b[4 + j] = hi[j]; }
          bf[rr][p] = b;
        }
      __builtin_amdgcn_s_setprio(1);
#pragma unroll
      for (int ot = 0; ot < 4; ++ot)
#pragma unroll
        for (int rr = 0; rr < 2; ++rr)
#pragma unroll
          for (int p = 0; p < 4; ++p)
            acc[rr][ot][p] = __builtin_amdgcn_mfma_f32_16x16x32_bf16(
                afc[ot], bf[rr][p], acc[rr][ot][p], 0, 0, 0);
      __builtin_amdgcn_s_setprio(0);
      if (s < 24) {
#pragma unroll
        for (int ot = 0; ot < 4; ++ot) afc[ot] = afn[ot];
      }
    }
  }

  float* slds = FINAL ? (float*)xt : (float*)&xt[36864];

  if (FINAL) {
    // fp32 NCHW direct stores
    float* out = (float*)outp;
#pragma unroll
    for (int rr = 0; rr < 2; ++rr)
#pragma unroll
      for (int ot = 0; ot < 4; ++ot)
#pragma unroll
        for (int p = 0; p < 4; ++p)
#pragma unroll
          for (int r = 0; r < 4; ++r) {
            int oo = ot * 16 + quad * 4 + r;
            long off = ((long)(n * 64 + oo) << 16) + (r0 + w + rr * 4) * 256 + x0 + p * 16 + l15;
            out[off] = acc[rr][ot][p][r];
          }
    // ---- fused BN-stats partials ----
    __syncthreads();  // all xt reads done
#pragma unroll
    for (int ot = 0; ot < 4; ++ot)
#pragma unroll
      for (int r = 0; r < 4; ++r) {
        float s = 0.f, q = 0.f;
#pragma unroll
        for (int rr = 0; rr < 2; ++rr)
#pragma unroll
          for (int p = 0; p < 4; ++p) {
            float v = acc[rr][ot][p][r];
            s += v; q += v * v;
          }
#pragma unroll
        for (int m = 1; m < 16; m <<= 1) {
          s += __shfl_xor(s, m);
          q += __shfl_xor(q, m);
        }
        if (l15 == 0) {
          int ch = ot * 16 + quad * 4 + r;
          slds[w * 128 + ch] = s;
          slds[w * 128 + 64 + ch] = q;
        }
      }
    __syncthreads();
    if (tid < 128) {
      float v = slds[tid] + slds[128 + tid] + slds[256 + tid] + slds[384 + tid];
      partials[(long)tid * NB + bid] = v;
    }
  } else {
    __syncthreads();  // all xt reads done before aliasing
    // bf16 NHWC via LDS bounce (cbuf = xt[0..36863]) + stats into slds
    short* cbuf = xt;
#pragma unroll
    for (int rr = 0; rr < 2; ++rr)
#pragma unroll
      for (int ot = 0; ot < 4; ++ot)
#pragma unroll
        for (int p = 0; p < 4; ++p) {
          short4v pk;
#pragma unroll
          for (int r = 0; r < 4; ++r) pk[r] = f2bf_s(acc[rr][ot][p][r]);
          *(short4v*)&cbuf[((w + rr * 4) * 64 + p * 16 + l15) * 72 + ot * 16 + quad * 4] = pk;
        }
#pragma unroll
    for (int ot = 0; ot < 4; ++ot)
#pragma unroll
      for (int r = 0; r < 4; ++r) {
        float s = 0.f, q = 0.f;
#pragma unroll
        for (int rr = 0; rr < 2; ++rr)
#pragma unroll
          for (int p = 0; p < 4; ++p) {
            float v = acc[rr][ot][p][r];
            s += v; q += v * v;
          }
#pragma unroll
        for (int m = 1; m < 16; m <<= 1) {
          s += __shfl_xor(s, m);
          q += __shfl_xor(q, m);
        }
        if (l15 == 0) {
          int ch = ot * 16 + quad * 4 + r;
          slds[w * 128 + ch] = s;
          slds[w * 128 + 64 + ch] = q;
        }
      }
    __syncthreads();
    short* hout = (short*)outp;
    for (int idx = tid; idx < 4096; idx += 256) {
      int w2 = idx >> 9, rem = idx & 511;
      int px = rem >> 3, ch = rem & 7;
      short8 v = *(const short8*)&cbuf[(w2 * 64 + px) * 72 + ch * 8];
      *(short8*)&hout[(((long)(n * 256 + r0 + w2) * 256) + x0 + px) * 64 + ch * 8] = v;
    }
    if (tid < 128) {
      float v = slds[tid] + slds[128 + tid] + slds[256 + tid] + slds[384 + tid];
      partials[(long)tid * NB + bid] = v;
    }
  }
}

// ---------------- finalize BN: stats -> per-channel scale/shift ----------------
__global__ void finalize_mode_kernel(const float* __restrict__ stats,
                                     float* __restrict__ params,
                                     const void* __restrict__ gamma,
                                     const void* __restrict__ beta,
                                     const void* __restrict__ xprobe) {
  __shared__ int sflag;
  int isf = block_detect_isf(xprobe, &sflag);
  int o = threadIdx.x;
  if (o < MK_CO) {
    const float M = (float)(MK_N * MK_H * MK_W);
    float mean = stats[o] / M;
    float var = stats[MK_CO + o] / M - mean * mean;
    float inv = rsqrtf(var + MK_EPS);
    float sc = rdv(gamma, o, isf) * inv;
    params[o] = sc;
    params[MK_CO + o] = rdv(beta, o, isf) - mean * sc;
  }
}

// ---------------- in-place BN + ReLU, fp32 NCHW, float4 grid-stride ----------------
__global__ __launch_bounds__(256) void bn_relu_f32v(float4* __restrict__ y,
                                                    const float* __restrict__ params) {
  const long total = (long)MK_N * MK_CO * MK_H * MK_W / 4;  // 8388608
  for (long i = (long)blockIdx.x * 256 + threadIdx.x; i < total;
       i += (long)gridDim.x * 256) {
    int ch = (int)((i >> 14) & (MK_CO - 1));  // 16384 float4 per (n,ch) plane
    float sc = params[ch], sh = params[MK_CO + ch];
    float4 v = y[i];
    v.x = fmaxf(fmaf(v.x, sc, sh), 0.f);
    v.y = fmaxf(fmaf(v.y, sc, sh), 0.f);
    v.z = fmaxf(fmaf(v.z, sc, sh), 0.f);
    v.w = fmaxf(fmaf(v.w, sc, sh), 0.f);
    y[i] = v;
  }
}

extern "C" void kernel_launch(void* const* d_in, const int* in_sizes, int n_in,
                              void* d_out, int out_size, void* d_ws, size_t ws_size,
                              hipStream_t stream) {
  const void* x     = d_in[0];
  const void* t     = d_in[1];
  const void* w5_1  = d_in[2];
  const void* w3_1  = d_in[3];
  const void* w1_1  = d_in[4];
  const void* a3_1  = d_in[5];
  const void* a5_1  = d_in[6];
  const void* gw_1  = d_in[7];
  const void* gb_1  = d_in[8];
  const void* gamma_1 = d_in[9];
  const void* beta_1  = d_in[10];
  const void* w5_2  = d_in[11];
  const void* w3_2  = d_in[12];
  const void* w1_2  = d_in[13];
  const void* a3_2  = d_in[14];
  const void* a5_2  = d_in[15];
  const void* gw_2  = d_in[16];
  const void* gb_2  = d_in[17];
  const void* gamma_2 = d_in[18];
  const void* beta_2  = d_in[19];

  // Memory map (d_out = 128 MiB, ws = 64 MiB):
  //   d_out[0:32M)        : x_nhwc (dead after conv1; overwritten by conv2A out)
  //   d_out[32M]          : st1 (512B)   d_out[32M+4K]: partials1 (512KB)
  //   d_out[34M]          : P1 panels (819200 B, dead after conv1)
  //   d_out[100M]         : P2 panels (1638400 B) + pr1_hi (512 B) right after
  //   d_out[126M]         : partials2a (256KB; reduced before conv2B clobbers)
  //   d_out[0:128M)       : final fp32 NCHW out (conv2A n0-3 -> [0,64M),
  //                         conv2B n4-7 -> [64M,128M))
  //   ws[0:64M)           : h bf16 NHWC. After conv2A, ws[0:32M) (n0-3) dead:
  //   ws[0]: st2/pr2      ws[4K]: partials2b (256KB)   ws[2M]: P2+pr1 copy
  char* dob = (char*)d_out;
  short* x_nhwc = (short*)d_out;
  float* st1   = (float*)(dob + 33554432);
  float* part1 = (float*)(dob + 33554432 + 4096);
  short* P1    = (short*)(dob + 35651584);
  short* P2    = (short*)(dob + 104857600);
  float* pr1_hi = (float*)(dob + 104857600 + 1638400);
  float* part2a = (float*)(dob + 132120576);  // 126 MiB
  float* out = (float*)d_out;

  char* wsb = (char*)d_ws;
  short* h     = (short*)d_ws;
  float* st2   = (float*)d_ws;
  float* pr2   = st2 + 128;
  float* part2b = (float*)(wsb + 4096);
  short* P2c   = (short*)(wsb + 2097152);
  float* pr1c  = (float*)(wsb + 2097152 + 1638400);

  // ---- panels (both layers depend only on t + weight inputs) ----
  make_panels<32><<<dim3(25, 8), 256, 0, stream>>>(t, gw_1, gb_1, w5_1, w3_1, w1_1, a3_1, a5_1, P1, x);
  make_panels<64><<<dim3(25, 8), 256, 0, stream>>>(t, gw_2, gb_2, w5_2, w3_2, w1_2, a3_2, a5_2, P2, x);

  // ---- layer 1 ----
  x_to_nhwc<<<dim3(4, 256, 8), 256, 0, stream>>>(x, x_nhwc, x);
  zero128_kernel<<<1, 128, 0, stream>>>(st1);
  conv_mfma<32, false, false><<<dim3(4, 32, 8), 256, 0, stream>>>(
      x_nhwc, P1, h, 0, nullptr, part1, 1024);
  reduce_partials<<<128, 256, 0, stream>>>(part1, st1, 1024);
  finalize_mode_kernel<<<1, 64, 0, stream>>>(st1, pr1_hi, gamma_1, beta_1, x);

  // ---- layer 2 (layer-1 BN+ReLU fused into staging; split halves so panels /
  //      partials are never read after being overwritten) ----
  conv_mfma<64, true, true><<<dim3(4, 32, 4), 256, 0, stream>>>(
      h, P2, out, 0, pr1_hi, part2a, 512);
  zero128_kernel<<<1, 128, 0, stream>>>(st2);               // h n0-3 now dead
  reduce_partials<<<128, 256, 0, stream>>>(part2a, st2, 512);
  copy16<<<401, 256, 0, stream>>>((const short8*)P2, (short8*)P2c, 102432);  // P2 + pr1
  conv_mfma<64, true, true><<<dim3(4, 32, 4), 256, 0, stream>>>(
      h, P2c, out, 4, pr1c, part2b, 512);
  reduce_partials<<<128, 256, 0, stream>>>(part2b, st2, 512);
  finalize_mode_kernel<<<1, 64, 0, stream>>>(st2, pr2, gamma_2, beta_2, x);
  bn_relu_f32v<<<2048, 256, 0, stream>>>((float4*)out, pr2);
}

// Round 7
// 458.353 us; speedup vs baseline: 6.4754x; 1.0232x over previous
//
#include <hip/hip_runtime.h>
#include <hip/hip_bf16.h>

#define MK_N 8
#define MK_T 8
#define MK_H 256
#define MK_W 256
#define MK_CO 64
#define MK_EPS 1e-5f

typedef __attribute__((ext_vector_type(8))) short short8;
typedef __attribute__((ext_vector_type(4))) short short4v;
typedef __attribute__((ext_vector_type(4))) float f32x4;

// read element idx from p, which is fp32 (isf32=1) or bf16 (isf32=0)
__device__ __forceinline__ float rdv(const void* p, long idx, int isf32) {
  return isf32 ? ((const float*)p)[idx]
               : __bfloat162float(((const __hip_bfloat16*)p)[idx]);
}

__device__ __forceinline__ short f2bf_s(float f) {
  __hip_bfloat16 b = __float2bfloat16(f);
  union { __hip_bfloat16 b; short s; } u; u.b = b; return u.s;
}
__device__ __forceinline__ float bfu2f(unsigned short s) {
  return __uint_as_float((unsigned)s << 16);
}

// Inline dtype probe on pristine x: bf16 -> sane exponents; fp32 -> ~45% insane.
__device__ __forceinline__ int block_detect_isf(const void* xprobe, int* sflag) {
  if (threadIdx.x < 64) {
    const unsigned short* u16 = (const unsigned short*)xprobe;
    int insane = 0;
#pragma unroll
    for (int j = 0; j < 4; ++j) {
      unsigned short u = u16[threadIdx.x * 4 + j];
      int e = (u >> 7) & 0xFF;
      bool zero = (u & 0x7FFF) == 0;
      if (!(zero || (e >= 0x60 && e <= 0x85))) insane++;
    }
#pragma unroll
    for (int off = 32; off > 0; off >>= 1) insane += __shfl_down(insane, off);
    if (threadIdx.x == 0) *sflag = (insane > 32) ? 1 : 0;
  }
  __syncthreads();
  return *sflag;
}

// ---------------- x (NCHW, fp32|bf16) -> NHWC bf16 ----------------
__global__ __launch_bounds__(256) void x_to_nhwc(const void* __restrict__ x,
                                                 short* __restrict__ xo,
                                                 const void* __restrict__ xprobe) {
  __shared__ float xl[32 * 65];
  __shared__ int sflag;
  int isf = block_detect_isf(xprobe, &sflag);
  int n = blockIdx.z, y = blockIdx.y, x0 = blockIdx.x * 64;
  int tid = threadIdx.x;
  {
    int c = tid >> 3, ch = tid & 7;
    long base = ((long)(n * 32 + c) * 256 + y) * 256 + x0 + ch * 8;
#pragma unroll
    for (int j = 0; j < 8; ++j) xl[c * 65 + ch * 8 + j] = rdv(x, base + j, isf);
  }
  __syncthreads();
  {
    int xi = tid >> 2, cc = tid & 3;
    short8 v;
#pragma unroll
    for (int j = 0; j < 8; ++j) v[j] = f2bf_s(xl[(cc * 8 + j) * 65 + xi]);
    *(short8*)&xo[(((long)(n * 256 + y) * 256) + x0 + xi) * 32 + cc * 8] = v;
  }
}

// ---------------- panel precompute, BOTH layers in one dispatch ----------------
// grid (25 s, 8 n, 2 layer). Panel layout: [n][hc][s][o=64][c=32] bf16.
__global__ __launch_bounds__(256) void make_panels_dual(
    const void* __restrict__ t,
    const void* __restrict__ gw1, const void* __restrict__ gb1,
    const void* __restrict__ w51, const void* __restrict__ w31,
    const void* __restrict__ w11, const void* __restrict__ a31,
    const void* __restrict__ a51, short* __restrict__ p1,
    const void* __restrict__ gw2, const void* __restrict__ gb2,
    const void* __restrict__ w52, const void* __restrict__ w32,
    const void* __restrict__ w12, const void* __restrict__ a32,
    const void* __restrict__ a52, short* __restrict__ p2,
    const void* __restrict__ xprobe) {
  __shared__ float slog[320], sgate[320];
  __shared__ int sflag;
  const int s = blockIdx.x, n = blockIdx.y, lay = blockIdx.z;
  const int tid = threadIdx.x;
  const int isf = block_detect_isf(xprobe, &sflag);

  const void* gw = lay ? gw2 : gw1;
  const void* gb = lay ? gb2 : gb1;
  const void* w5 = lay ? w52 : w51;
  const void* w3 = lay ? w32 : w31;
  const void* w1 = lay ? w12 : w11;
  const void* a3 = lay ? a32 : a31;
  const void* a5 = lay ? a52 : a51;
  short* pan = lay ? p2 : p1;
  const int CI = lay ? 64 : 32;
  const int HC = CI / 32;

  for (int eo = tid; eo < 320; eo += 256) {
    int e = eo >> 6, o = eo & 63;
    long row = e * 64 + o;
    float sacc = rdv(gb, row, isf);
#pragma unroll
    for (int k = 0; k < MK_T; ++k)
      sacc += rdv(t, n * MK_T + k, isf) * rdv(gw, row * MK_T + k, isf);
    slog[e * 64 + o] = sacc;
  }
  __syncthreads();
  if (tid < 64) {
    float m = slog[tid];
#pragma unroll
    for (int e = 1; e < 5; ++e) m = fmaxf(m, slog[e * 64 + tid]);
    float tmp[5], sum = 0.f;
#pragma unroll
    for (int e = 0; e < 5; ++e) { tmp[e] = expf(slog[e * 64 + tid] - m); sum += tmp[e]; }
    float inv = 1.f / sum;
#pragma unroll
    for (int e = 0; e < 5; ++e) sgate[tid * 5 + e] = tmp[e] * inv;
  }
  __syncthreads();

  const int mo = tid >> 2, gq = tid & 3;
  float ge[5];
#pragma unroll
  for (int e = 0; e < 5; ++e) ge[e] = sgate[mo * 5 + e];

  const int ky = s / 5, kx = s - ky * 5;
  const bool in3 = (ky >= 1 && ky <= 3 && kx >= 1 && kx <= 3);
  for (int hc = 0; hc < HC; ++hc) {
    short8 pk;
#pragma unroll
    for (int j = 0; j < 8; ++j) {
      long oc = (long)mo * CI + hc * 32 + gq * 8 + j;
      float pa3 = rdv(a3, oc, isf) * (1.f / 27.f);
      float pa5 = rdv(a5, oc, isf) * (1.f / 125.f);
      float v = ge[0] * rdv(w5, oc * 25 + s, isf);
      if (in3) {
        v += ge[1] * rdv(w3, oc * 9 + (ky - 1) * 3 + (kx - 1), isf);
        v += ge[3] * pa3;
      }
      if (s == 12) v += ge[2] * rdv(w1, oc, isf);
      v += ge[4] * pa5;
      pk[j] = f2bf_s(v);
    }
    *(short8*)&pan[((((long)n * HC + hc) * 25 + s) * 64 + mo) * 32 + gq * 8] = pk;
  }
}

// ---------------- trivial 16B copy ----------------
__global__ __launch_bounds__(256) void copy16(const short8* __restrict__ src,
                                              short8* __restrict__ dst, int n16) {
  int i = blockIdx.x * 256 + threadIdx.x;
  if (i < n16) dst[i] = src[i];
}

// ---------------- reduce partials (+optional carry-in) and/or finalize BN ----------------
// grid 64: block o sums part[o][0:nb] and part[64+o][0:nb].
// stin: add previous sums. stout: store raw sums. params: finalize scale/shift.
__global__ __launch_bounds__(256) void reduce_finalize(
    const float* __restrict__ part, int nb,
    const float* __restrict__ stin, float* __restrict__ stout,
    float* __restrict__ params,
    const void* __restrict__ gamma, const void* __restrict__ beta,
    const void* __restrict__ xprobe) {
  __shared__ float rs[256], rq[256];
  __shared__ int sflag;
  const int isf = block_detect_isf(xprobe, &sflag);
  const int o = blockIdx.x;
  const int tid = threadIdx.x;
  float s = 0.f, q = 0.f;
  for (int k = tid; k < nb; k += 256) {
    s += part[(long)o * nb + k];
    q += part[(long)(64 + o) * nb + k];
  }
  rs[tid] = s; rq[tid] = q;
  __syncthreads();
  if (tid < 64) {
    s = rs[tid] + rs[tid + 64] + rs[tid + 128] + rs[tid + 192];
    q = rq[tid] + rq[tid + 64] + rq[tid + 128] + rq[tid + 192];
#pragma unroll
    for (int off = 32; off > 0; off >>= 1) {
      s += __shfl_down(s, off);
      q += __shfl_down(q, off);
    }
    if (tid == 0) {
      if (stin) { s += stin[o]; q += stin[64 + o]; }
      if (stout) { stout[o] = s; stout[64 + o] = q; }
      if (params) {
        const float M = (float)(MK_N * MK_H * MK_W);
        float mean = s / M;
        float var = q / M - mean * mean;
        float inv = rsqrtf(var + MK_EPS);
        float sc = rdv(gamma, o, isf) * inv;
        params[o] = sc;
        params[MK_CO + o] = rdv(beta, o, isf) - mean * sc;
      }
    }
  }
}

// ---------------- MFMA implicit-GEMM conv, 8-row blocks ----------------
// Block: 256 thr (4 waves). Tile: [CO=64] x [8 rows] x [64 cols], sample n.
// Each wave owns rows {w, w+4}: 32 MFMAs per s-iter vs 4 global A-loads;
// 2-deep A prefetch covers L2 latency (~200-300cy) fully.
// Fused epilogue: per-block per-channel BN partial sums (from fp32 acc).
// BNIN: apply layer-1 BN scale/shift + ReLU while staging input.
template <int CI, bool FINAL, bool BNIN>
__global__ __launch_bounds__(256, 2) void conv_mfma(
    const short* __restrict__ xsrc,   // NHWC bf16 [8][256][256][CI]
    const short* __restrict__ pan,    // [n][hc][s][64][32] bf16
    void* __restrict__ outp,          // FINAL ? float* NCHW : short* NHWC bf16
    int nbase,
    const float* __restrict__ pr,     // BNIN: [64] scale, [64] shift
    float* __restrict__ partials,     // [128][NB]
    int NB)
{
  // xt: 12 rows x 68 cols x 36-short pad = 29376 shorts.
  // non-FINAL also needs cbuf 8*64*72=36864 + slds 1024 shorts (aliased).
  constexpr int XT_SH = FINAL ? 29376 : 37888;
  __shared__ short xt[XT_SH];
  __shared__ float spr[128];

  const int tid = threadIdx.x;
  const int x0 = blockIdx.x * 64;
  const int r0 = blockIdx.y * 8;
  const int n = blockIdx.z + nbase;
  const int bid = (blockIdx.z * gridDim.y + blockIdx.y) * gridDim.x + blockIdx.x;

  if (BNIN) {
    if (tid < 128) spr[tid] = pr[tid];
  }

  const int lane = tid & 63, w = tid >> 6;
  const int quad = lane >> 4, l15 = lane & 15;

  int baseB[2][4];
#pragma unroll
  for (int rr = 0; rr < 2; ++rr)
#pragma unroll
    for (int p = 0; p < 4; ++p)
      baseB[rr][p] = ((w + rr * 4) * 68 + p * 16 + l15) * 36 + quad * 8;
  int aoff[4];
#pragma unroll
  for (int ot = 0; ot < 4; ++ot)
    aoff[ot] = (ot * 16 + l15) * 32 + quad * 8;

  f32x4 acc[2][4][4];
#pragma unroll
  for (int rr = 0; rr < 2; ++rr)
#pragma unroll
    for (int ot = 0; ot < 4; ++ot)
#pragma unroll
      for (int p = 0; p < 4; ++p) acc[rr][ot][p] = f32x4{0.f, 0.f, 0.f, 0.f};

  const int HC = CI / 32;
#pragma unroll 1
  for (int hc = 0; hc < HC; ++hc) {
    const int cbase = hc * 32;
    __syncthreads();  // xt WAR (hc>0) + spr visibility

    // ---- stage x tile (12 rows x 68 cols x 32 ch), optional fused BN+ReLU ----
    for (int idx = tid; idx < 12 * 68 * 4; idx += 256) {
      int r = idx / (68 * 4);
      int rem = idx - r * (68 * 4);
      int col = rem >> 2, ch = rem & 3;
      int gy = r0 - 2 + r, gx = x0 - 2 + col;
      short8 v = short8{0, 0, 0, 0, 0, 0, 0, 0};
      if ((unsigned)gy < 256u && (unsigned)gx < 256u) {
        v = *(const short8*)&xsrc[(((long)(n * 256 + gy) * 256) + gx) * CI + cbase + ch * 8];
        if (BNIN) {
#pragma unroll
          for (int j = 0; j < 8; ++j) {
            int c = cbase + ch * 8 + j;
            float f = bfu2f((unsigned short)v[j]);
            v[j] = f2bf_s(fmaxf(fmaf(f, spr[c], spr[64 + c]), 0.f));
          }
        }
      }
      short4v lo, hi;
#pragma unroll
      for (int j = 0; j < 4; ++j) { lo[j] = v[j]; hi[j] = v[4 + j]; }
      int sb = (r * 68 + col) * 36 + ch * 8;
      *(short4v*)&xt[sb] = lo;
      *(short4v*)&xt[sb + 4] = hi;
    }
    __syncthreads();

    const short* ps = pan + (((long)n * HC + hc) * 25) * 2048;

    // 2-deep A prefetch: s=0 and s=1 in flight before the loop
    short8 afc[4], afn[4];
#pragma unroll
    for (int ot = 0; ot < 4; ++ot) {
      afc[ot] = *(const short8*)&ps[aoff[ot]];
      afn[ot] = *(const short8*)&ps[2048 + aoff[ot]];
    }

#pragma unroll
    for (int s = 0; s < 25; ++s) {
      const int ky = s / 5, kx = s - ky * 5;
      const int koff = (ky * 68 + kx) * 36;
      short8 af2[4];
      if (s < 23) {
#pragma unroll
        for (int ot = 0; ot < 4; ++ot)
          af2[ot] = *(const short8*)&ps[(s + 2) * 2048 + aoff[ot]];
      }
      short8 bf[2][4];
#pragma unroll
      for (int rr = 0; rr < 2; ++rr)
#pragma unroll
        for (int p = 0; p < 4; ++p) {
          short4v lo = *(const short4v*)&xt[baseB[rr][p] + koff];
          short4v hi = *(const short4v*)&xt[baseB[rr][p] + koff + 4];
          short8 b;
#pragma unroll
          for (int j = 0; j < 4; ++j) { b[j] = lo[j]; b[4 + j] = hi[j]; }
          bf[rr][p] = b;
        }
      __builtin_amdgcn_s_setprio(1);
#pragma unroll
      for (int ot = 0; ot < 4; ++ot)
#pragma unroll
        for (int rr = 0; rr < 2; ++rr)
#pragma unroll
          for (int p = 0; p < 4; ++p)
            acc[rr][ot][p] = __builtin_amdgcn_mfma_f32_16x16x32_bf16(
                afc[ot], bf[rr][p], acc[rr][ot][p], 0, 0, 0);
      __builtin_amdgcn_s_setprio(0);
      if (s < 24) {
#pragma unroll
        for (int ot = 0; ot < 4; ++ot) {
          afc[ot] = afn[ot];
          if (s < 23) afn[ot] = af2[ot];
        }
      }
    }
  }

  float* slds = FINAL ? (float*)xt : (float*)&xt[36864];

  if (FINAL) {
    // fp32 NCHW direct stores
    float* out = (float*)outp;
#pragma unroll
    for (int rr = 0; rr < 2; ++rr)
#pragma unroll
      for (int ot = 0; ot < 4; ++ot)
#pragma unroll
        for (int p = 0; p < 4; ++p)
#pragma unroll
          for (int r = 0; r < 4; ++r) {
            int oo = ot * 16 + quad * 4 + r;
            long off = ((long)(n * 64 + oo) << 16) + (r0 + w + rr * 4) * 256 + x0 + p * 16 + l15;
            out[off] = acc[rr][ot][p][r];
          }
    // ---- fused BN-stats partials ----
    __syncthreads();  // all xt reads done
#pragma unroll
    for (int ot = 0; ot < 4; ++ot)
#pragma unroll
      for (int r = 0; r < 4; ++r) {
        float s = 0.f, q = 0.f;
#pragma unroll
        for (int rr = 0; rr < 2; ++rr)
#pragma unroll
          for (int p = 0; p < 4; ++p) {
            float v = acc[rr][ot][p][r];
            s += v; q += v * v;
          }
#pragma unroll
        for (int m = 1; m < 16; m <<= 1) {
          s += __shfl_xor(s, m);
          q += __shfl_xor(q, m);
        }
        if (l15 == 0) {
          int ch = ot * 16 + quad * 4 + r;
          slds[w * 128 + ch] = s;
          slds[w * 128 + 64 + ch] = q;
        }
      }
    __syncthreads();
    if (tid < 128) {
      float v = slds[tid] + slds[128 + tid] + slds[256 + tid] + slds[384 + tid];
      partials[(long)tid * NB + bid] = v;
    }
  } else {
    __syncthreads();  // all xt reads done before aliasing
    // bf16 NHWC via LDS bounce (cbuf = xt[0..36863]) + stats into slds
    short* cbuf = xt;
#pragma unroll
    for (int rr = 0; rr < 2; ++rr)
#pragma unroll
      for (int ot = 0; ot < 4; ++ot)
#pragma unroll
        for (int p = 0; p < 4; ++p) {
          short4v pk;
#pragma unroll
          for (int r = 0; r < 4; ++r) pk[r] = f2bf_s(acc[rr][ot][p][r]);
          *(short4v*)&cbuf[((w + rr * 4) * 64 + p * 16 + l15) * 72 + ot * 16 + quad * 4] = pk;
        }
#pragma unroll
    for (int ot = 0; ot < 4; ++ot)
#pragma unroll
      for (int r = 0; r < 4; ++r) {
        float s = 0.f, q = 0.f;
#pragma unroll
        for (int rr = 0; rr < 2; ++rr)
#pragma unroll
          for (int p = 0; p < 4; ++p) {
            float v = acc[rr][ot][p][r];
            s += v; q += v * v;
          }
#pragma unroll
        for (int m = 1; m < 16; m <<= 1) {
          s += __shfl_xor(s, m);
          q += __shfl_xor(q, m);
        }
        if (l15 == 0) {
          int ch = ot * 16 + quad * 4 + r;
          slds[w * 128 + ch] = s;
          slds[w * 128 + 64 + ch] = q;
        }
      }
    __syncthreads();
    short* hout = (short*)outp;
    for (int idx = tid; idx < 4096; idx += 256) {
      int w2 = idx >> 9, rem = idx & 511;
      int px = rem >> 3, ch = rem & 7;
      short8 v = *(const short8*)&cbuf[(w2 * 64 + px) * 72 + ch * 8];
      *(short8*)&hout[(((long)(n * 256 + r0 + w2) * 256) + x0 + px) * 64 + ch * 8] = v;
    }
    if (tid < 128) {
      float v = slds[tid] + slds[128 + tid] + slds[256 + tid] + slds[384 + tid];
      partials[(long)tid * NB + bid] = v;
    }
  }
}

// ---------------- in-place BN + ReLU, fp32 NCHW, float4 grid-stride ----------------
__global__ __launch_bounds__(256) void bn_relu_f32v(float4* __restrict__ y,
                                                    const float* __restrict__ params) {
  const long total = (long)MK_N * MK_CO * MK_H * MK_W / 4;  // 8388608
  for (long i = (long)blockIdx.x * 256 + threadIdx.x; i < total;
       i += (long)gridDim.x * 256) {
    int ch = (int)((i >> 14) & (MK_CO - 1));  // 16384 float4 per (n,ch) plane
    float sc = params[ch], sh = params[MK_CO + ch];
    float4 v = y[i];
    v.x = fmaxf(fmaf(v.x, sc, sh), 0.f);
    v.y = fmaxf(fmaf(v.y, sc, sh), 0.f);
    v.z = fmaxf(fmaf(v.z, sc, sh), 0.f);
    v.w = fmaxf(fmaf(v.w, sc, sh), 0.f);
    y[i] = v;
  }
}

extern "C" void kernel_launch(void* const* d_in, const int* in_sizes, int n_in,
                              void* d_out, int out_size, void* d_ws, size_t ws_size,
                              hipStream_t stream) {
  const void* x     = d_in[0];
  const void* t     = d_in[1];
  const void* w5_1  = d_in[2];
  const void* w3_1  = d_in[3];
  const void* w1_1  = d_in[4];
  const void* a3_1  = d_in[5];
  const void* a5_1  = d_in[6];
  const void* gw_1  = d_in[7];
  const void* gb_1  = d_in[8];
  const void* gamma_1 = d_in[9];
  const void* beta_1  = d_in[10];
  const void* w5_2  = d_in[11];
  const void* w3_2  = d_in[12];
  const void* w1_2  = d_in[13];
  const void* a3_2  = d_in[14];
  const void* a5_2  = d_in[15];
  const void* gw_2  = d_in[16];
  const void* gb_2  = d_in[17];
  const void* gamma_2 = d_in[18];
  const void* beta_2  = d_in[19];

  // Memory map (d_out = 128 MiB, ws = 64 MiB):
  //   d_out[0:32M)        : x_nhwc (dead after conv1; overwritten by conv2A out)
  //   d_out[32M+4K]       : partials1 (512KB; consumed by reduce_finalize1)
  //   d_out[34M]          : P1 panels (819200 B, dead after conv1)
  //   d_out[100M]         : P2 panels (1638400 B) + pr1_hi (512 B) right after
  //   d_out[126M]         : partials2a (256KB; reduced before conv2B clobbers)
  //   d_out[0:128M)       : final fp32 NCHW out (conv2A n0-3 -> [0,64M),
  //                         conv2B n4-7 -> [64M,128M))
  //   ws[0:64M)           : h bf16 NHWC. After conv2A, ws[0:32M) (n0-3) dead:
  //   ws[0]: st2/pr2      ws[4K]: partials2b (256KB)   ws[2M]: P2+pr1 copy
  char* dob = (char*)d_out;
  short* x_nhwc = (short*)d_out;
  float* part1 = (float*)(dob + 33554432 + 4096);
  short* P1    = (short*)(dob + 35651584);
  short* P2    = (short*)(dob + 104857600);
  float* pr1_hi = (float*)(dob + 104857600 + 1638400);
  float* part2a = (float*)(dob + 132120576);  // 126 MiB
  float* out = (float*)d_out;

  char* wsb = (char*)d_ws;
  short* h     = (short*)d_ws;
  float* st2   = (float*)d_ws;
  float* pr2   = st2 + 128;
  float* part2b = (float*)(wsb + 4096);
  short* P2c   = (short*)(wsb + 2097152);
  float* pr1c  = (float*)(wsb + 2097152 + 1638400);

  // ---- panels (both layers depend only on t + weight inputs) ----
  make_panels_dual<<<dim3(25, 8, 2), 256, 0, stream>>>(
      t, gw_1, gb_1, w5_1, w3_1, w1_1, a3_1, a5_1, P1,
      gw_2, gb_2, w5_2, w3_2, w1_2, a3_2, a5_2, P2, x);

  // ---- layer 1 ----
  x_to_nhwc<<<dim3(4, 256, 8), 256, 0, stream>>>(x, x_nhwc, x);
  conv_mfma<32, false, false><<<dim3(4, 32, 8), 256, 0, stream>>>(
      x_nhwc, P1, h, 0, nullptr, part1, 1024);
  reduce_finalize<<<64, 256, 0, stream>>>(part1, 1024, nullptr, nullptr,
                                          pr1_hi, gamma_1, beta_1, x);

  // ---- layer 2 (layer-1 BN+ReLU fused into staging; split halves so panels /
  //      partials are never read after being overwritten) ----
  conv_mfma<64, true, true><<<dim3(4, 32, 4), 256, 0, stream>>>(
      h, P2, out, 0, pr1_hi, part2a, 512);
  reduce_finalize<<<64, 256, 0, stream>>>(part2a, 512, nullptr, st2,
                                          nullptr, nullptr, nullptr, x);
  copy16<<<401, 256, 0, stream>>>((const short8*)P2, (short8*)P2c, 102432);  // P2 + pr1
  conv_mfma<64, true, true><<<dim3(4, 32, 4), 256, 0, stream>>>(
      h, P2c, out, 4, pr1c, part2b, 512);
  reduce_finalize<<<64, 256, 0, stream>>>(part2b, 512, st2, nullptr,
                                          pr2, gamma_2, beta_2, x);
  bn_relu_f32v<<<2048, 256, 0, stream>>>((float4*)out, pr2);
}

// Round 8
// 436.863 us; speedup vs baseline: 6.7939x; 1.0492x over previous
//
#include <hip/hip_runtime.h>
#include <hip/hip_bf16.h>

#define MK_N 8
#define MK_T 8
#define MK_H 256
#define MK_W 256
#define MK_CO 64
#define MK_EPS 1e-5f

typedef __attribute__((ext_vector_type(8))) short short8;
typedef __attribute__((ext_vector_type(4))) short short4v;
typedef __attribute__((ext_vector_type(4))) float f32x4;

// read element idx from p, which is fp32 (isf32=1) or bf16 (isf32=0)
__device__ __forceinline__ float rdv(const void* p, long idx, int isf32) {
  return isf32 ? ((const float*)p)[idx]
               : __bfloat162float(((const __hip_bfloat16*)p)[idx]);
}

__device__ __forceinline__ short f2bf_s(float f) {
  __hip_bfloat16 b = __float2bfloat16(f);
  union { __hip_bfloat16 b; short s; } u; u.b = b; return u.s;
}
__device__ __forceinline__ float bfu2f(unsigned short s) {
  return __uint_as_float((unsigned)s << 16);
}

// Inline dtype probe on pristine x: bf16 -> sane exponents; fp32 -> ~45% insane.
__device__ __forceinline__ int block_detect_isf(const void* xprobe, int* sflag) {
  if (threadIdx.x < 64) {
    const unsigned short* u16 = (const unsigned short*)xprobe;
    int insane = 0;
#pragma unroll
    for (int j = 0; j < 4; ++j) {
      unsigned short u = u16[threadIdx.x * 4 + j];
      int e = (u >> 7) & 0xFF;
      bool zero = (u & 0x7FFF) == 0;
      if (!(zero || (e >= 0x60 && e <= 0x85))) insane++;
    }
#pragma unroll
    for (int off = 32; off > 0; off >>= 1) insane += __shfl_down(insane, off);
    if (threadIdx.x == 0) *sflag = (insane > 32) ? 1 : 0;
  }
  __syncthreads();
  return *sflag;
}

// ---------------- panel precompute, BOTH layers in one dispatch ----------------
// grid (25 s, 8 n, 2 layer). Panel layout: [n][hc][s][o=64][c=32] bf16.
__global__ __launch_bounds__(256) void make_panels_dual(
    const void* __restrict__ t,
    const void* __restrict__ gw1, const void* __restrict__ gb1,
    const void* __restrict__ w51, const void* __restrict__ w31,
    const void* __restrict__ w11, const void* __restrict__ a31,
    const void* __restrict__ a51, short* __restrict__ p1,
    const void* __restrict__ gw2, const void* __restrict__ gb2,
    const void* __restrict__ w52, const void* __restrict__ w32,
    const void* __restrict__ w12, const void* __restrict__ a32,
    const void* __restrict__ a52, short* __restrict__ p2,
    const void* __restrict__ xprobe) {
  __shared__ float slog[320], sgate[320];
  __shared__ int sflag;
  const int s = blockIdx.x, n = blockIdx.y, lay = blockIdx.z;
  const int tid = threadIdx.x;
  const int isf = block_detect_isf(xprobe, &sflag);

  const void* gw = lay ? gw2 : gw1;
  const void* gb = lay ? gb2 : gb1;
  const void* w5 = lay ? w52 : w51;
  const void* w3 = lay ? w32 : w31;
  const void* w1 = lay ? w12 : w11;
  const void* a3 = lay ? a32 : a31;
  const void* a5 = lay ? a52 : a51;
  short* pan = lay ? p2 : p1;
  const int CI = lay ? 64 : 32;
  const int HC = CI / 32;

  for (int eo = tid; eo < 320; eo += 256) {
    int e = eo >> 6, o = eo & 63;
    long row = e * 64 + o;
    float sacc = rdv(gb, row, isf);
#pragma unroll
    for (int k = 0; k < MK_T; ++k)
      sacc += rdv(t, n * MK_T + k, isf) * rdv(gw, row * MK_T + k, isf);
    slog[e * 64 + o] = sacc;
  }
  __syncthreads();
  if (tid < 64) {
    float m = slog[tid];
#pragma unroll
    for (int e = 1; e < 5; ++e) m = fmaxf(m, slog[e * 64 + tid]);
    float tmp[5], sum = 0.f;
#pragma unroll
    for (int e = 0; e < 5; ++e) { tmp[e] = expf(slog[e * 64 + tid] - m); sum += tmp[e]; }
    float inv = 1.f / sum;
#pragma unroll
    for (int e = 0; e < 5; ++e) sgate[tid * 5 + e] = tmp[e] * inv;
  }
  __syncthreads();

  const int mo = tid >> 2, gq = tid & 3;
  float ge[5];
#pragma unroll
  for (int e = 0; e < 5; ++e) ge[e] = sgate[mo * 5 + e];

  const int ky = s / 5, kx = s - ky * 5;
  const bool in3 = (ky >= 1 && ky <= 3 && kx >= 1 && kx <= 3);
  for (int hc = 0; hc < HC; ++hc) {
    short8 pk;
#pragma unroll
    for (int j = 0; j < 8; ++j) {
      long oc = (long)mo * CI + hc * 32 + gq * 8 + j;
      float pa3 = rdv(a3, oc, isf) * (1.f / 27.f);
      float pa5 = rdv(a5, oc, isf) * (1.f / 125.f);
      float v = ge[0] * rdv(w5, oc * 25 + s, isf);
      if (in3) {
        v += ge[1] * rdv(w3, oc * 9 + (ky - 1) * 3 + (kx - 1), isf);
        v += ge[3] * pa3;
      }
      if (s == 12) v += ge[2] * rdv(w1, oc, isf);
      v += ge[4] * pa5;
      pk[j] = f2bf_s(v);
    }
    *(short8*)&pan[((((long)n * HC + hc) * 25 + s) * 64 + mo) * 32 + gq * 8] = pk;
  }
}

// ---------------- trivial 16B copy ----------------
__global__ __launch_bounds__(256) void copy16(const short8* __restrict__ src,
                                              short8* __restrict__ dst, int n16) {
  int i = blockIdx.x * 256 + threadIdx.x;
  if (i < n16) dst[i] = src[i];
}

// ---------------- reduce partials (+optional carry-in) and/or finalize BN ----------------
// grid 64: block o sums part[o][0:nb] and part[64+o][0:nb].
// stin: add previous sums. stout: store raw sums. params: finalize scale/shift.
__global__ __launch_bounds__(256) void reduce_finalize(
    const float* __restrict__ part, int nb,
    const float* __restrict__ stin, float* __restrict__ stout,
    float* __restrict__ params,
    const void* __restrict__ gamma, const void* __restrict__ beta,
    const void* __restrict__ xprobe) {
  __shared__ float rs[256], rq[256];
  __shared__ int sflag;
  const int isf = block_detect_isf(xprobe, &sflag);
  const int o = blockIdx.x;
  const int tid = threadIdx.x;
  float s = 0.f, q = 0.f;
  for (int k = tid; k < nb; k += 256) {
    s += part[(long)o * nb + k];
    q += part[(long)(64 + o) * nb + k];
  }
  rs[tid] = s; rq[tid] = q;
  __syncthreads();
  if (tid < 64) {
    s = rs[tid] + rs[tid + 64] + rs[tid + 128] + rs[tid + 192];
    q = rq[tid] + rq[tid + 64] + rq[tid + 128] + rq[tid + 192];
#pragma unroll
    for (int off = 32; off > 0; off >>= 1) {
      s += __shfl_down(s, off);
      q += __shfl_down(q, off);
    }
    if (tid == 0) {
      if (stin) { s += stin[o]; q += stin[64 + o]; }
      if (stout) { stout[o] = s; stout[64 + o] = q; }
      if (params) {
        const float M = (float)(MK_N * MK_H * MK_W);
        float mean = s / M;
        float var = q / M - mean * mean;
        float inv = rsqrtf(var + MK_EPS);
        float sc = rdv(gamma, o, isf) * inv;
        params[o] = sc;
        params[MK_CO + o] = rdv(beta, o, isf) - mean * sc;
      }
    }
  }
}

// ---------------- MFMA implicit-GEMM conv, 8-row blocks ----------------
// Block: 256 thr (4 waves). Tile: [CO=64] x [8 rows] x [64 cols], sample n.
// Each wave owns rows {w, w+4}: 32 MFMAs per s-iter; s-loop is barrier-free and
// fully unrolled (compiler software-pipelines A-loads/B-reads itself).
// NCHW: stage directly from NCHW fp32|bf16 input (fused transpose, conv1).
// BNIN: apply layer-1 BN scale/shift + ReLU while staging NHWC bf16 (conv2).
// Fused epilogue: per-block per-channel BN partial sums (from fp32 acc).
template <int CI, bool FINAL, bool BNIN, bool NCHW>
__global__ __launch_bounds__(256, 2) void conv_mfma(
    const void* __restrict__ xsrc,    // NCHW ? [8][CI][256][256] f32|bf16 : NHWC bf16
    const void* __restrict__ xprobe,  // pristine x for dtype probe (NCHW only)
    const short* __restrict__ pan,    // [n][hc][s][64][32] bf16
    void* __restrict__ outp,          // FINAL ? float* NCHW : short* NHWC bf16
    int nbase,
    const float* __restrict__ pr,     // BNIN: [64] scale, [64] shift
    float* __restrict__ partials,     // [128][NB]
    int NB)
{
  // xt: 12 rows x 68 cols x 36-short pad = 29376 shorts.
  // non-FINAL also needs cbuf 8*64*72=36864 + slds 1024 shorts (aliased).
  constexpr int XT_SH = FINAL ? 29376 : 37888;
  __shared__ short xt[XT_SH];
  __shared__ float spr[128];
  __shared__ int sflag;

  const int tid = threadIdx.x;
  const int x0 = blockIdx.x * 64;
  const int r0 = blockIdx.y * 8;
  const int n = blockIdx.z + nbase;
  const int bid = (blockIdx.z * gridDim.y + blockIdx.y) * gridDim.x + blockIdx.x;

  int isf = 0;
  if (NCHW) isf = block_detect_isf(xprobe, &sflag);  // includes __syncthreads

  if (BNIN) {
    if (tid < 128) spr[tid] = pr[tid];
  }

  const int lane = tid & 63, w = tid >> 6;
  const int quad = lane >> 4, l15 = lane & 15;

  int baseB[2][4];
#pragma unroll
  for (int rr = 0; rr < 2; ++rr)
#pragma unroll
    for (int p = 0; p < 4; ++p)
      baseB[rr][p] = ((w + rr * 4) * 68 + p * 16 + l15) * 36 + quad * 8;
  int aoff[4];
#pragma unroll
  for (int ot = 0; ot < 4; ++ot)
    aoff[ot] = (ot * 16 + l15) * 32 + quad * 8;

  f32x4 acc[2][4][4];
#pragma unroll
  for (int rr = 0; rr < 2; ++rr)
#pragma unroll
    for (int ot = 0; ot < 4; ++ot)
#pragma unroll
      for (int p = 0; p < 4; ++p) acc[rr][ot][p] = f32x4{0.f, 0.f, 0.f, 0.f};

  const int HC = CI / 32;
#pragma unroll 1
  for (int hc = 0; hc < HC; ++hc) {
    const int cbase = hc * 32;
    __syncthreads();  // xt WAR (hc>0) + spr visibility

    if (NCHW) {
      // ---- stage from NCHW: fused transpose. item = (c, r, aligned 4-col grp) ----
      // gx0 = x0-4+4g keeps global reads 16B-aligned; LDS col = g*4+j-2.
      for (int idx = tid; idx < 32 * 12 * 18; idx += 256) {
        int c = idx / 216;
        int rem = idx - c * 216;
        int r = rem / 18, g = rem - r * 18;
        int gy = r0 - 2 + r;
        int gx0 = x0 - 4 + g * 4;
        long base = ((long)(n * 32 + c) * 256 + gy) * 256 + gx0;
        float f[4];
        bool rowok = (unsigned)gy < 256u;
        if (rowok && gx0 >= 0 && gx0 + 3 < 256) {
          if (isf) {
            float4 v = *(const float4*)((const float*)xsrc + base);
            f[0] = v.x; f[1] = v.y; f[2] = v.z; f[3] = v.w;
          } else {
            short4v v = *(const short4v*)((const short*)xsrc + base);
#pragma unroll
            for (int j = 0; j < 4; ++j) f[j] = bfu2f((unsigned short)v[j]);
          }
        } else if (rowok) {
#pragma unroll
          for (int j = 0; j < 4; ++j) {
            int gx = gx0 + j;
            f[j] = ((unsigned)gx < 256u) ? rdv(xsrc, base + j, isf) : 0.f;
          }
        } else {
          f[0] = f[1] = f[2] = f[3] = 0.f;
        }
#pragma unroll
        for (int j = 0; j < 4; ++j) {
          int col = g * 4 + j - 2;
          if ((unsigned)col < 68u) xt[(r * 68 + col) * 36 + c] = f2bf_s(f[j]);
        }
      }
    } else {
      // ---- stage from NHWC bf16 (12 rows x 68 cols x 32 ch), fused BN+ReLU ----
      const short* xs = (const short*)xsrc;
      for (int idx = tid; idx < 12 * 68 * 4; idx += 256) {
        int r = idx / (68 * 4);
        int rem = idx - r * (68 * 4);
        int col = rem >> 2, ch = rem & 3;
        int gy = r0 - 2 + r, gx = x0 - 2 + col;
        short8 v = short8{0, 0, 0, 0, 0, 0, 0, 0};
        if ((unsigned)gy < 256u && (unsigned)gx < 256u) {
          v = *(const short8*)&xs[(((long)(n * 256 + gy) * 256) + gx) * CI + cbase + ch * 8];
          if (BNIN) {
#pragma unroll
            for (int j = 0; j < 8; ++j) {
              int c = cbase + ch * 8 + j;
              float f = bfu2f((unsigned short)v[j]);
              v[j] = f2bf_s(fmaxf(fmaf(f, spr[c], spr[64 + c]), 0.f));
            }
          }
        }
        short4v lo, hi;
#pragma unroll
        for (int j = 0; j < 4; ++j) { lo[j] = v[j]; hi[j] = v[4 + j]; }
        int sb = (r * 68 + col) * 36 + ch * 8;
        *(short4v*)&xt[sb] = lo;
        *(short4v*)&xt[sb + 4] = hi;
      }
    }
    __syncthreads();

    const short* ps = pan + (((long)n * HC + hc) * 25) * 2048;

    // 1-deep A prefetch (compiler pipelines further on its own)
    short8 afc[4];
#pragma unroll
    for (int ot = 0; ot < 4; ++ot) afc[ot] = *(const short8*)&ps[aoff[ot]];

#pragma unroll
    for (int s = 0; s < 25; ++s) {
      const int ky = s / 5, kx = s - ky * 5;
      const int koff = (ky * 68 + kx) * 36;
      short8 afn[4];
      if (s < 24) {
#pragma unroll
        for (int ot = 0; ot < 4; ++ot)
          afn[ot] = *(const short8*)&ps[(s + 1) * 2048 + aoff[ot]];
      }
      short8 bf[2][4];
#pragma unroll
      for (int rr = 0; rr < 2; ++rr)
#pragma unroll
        for (int p = 0; p < 4; ++p) {
          short4v lo = *(const short4v*)&xt[baseB[rr][p] + koff];
          short4v hi = *(const short4v*)&xt[baseB[rr][p] + koff + 4];
          short8 b;
#pragma unroll
          for (int j = 0; j < 4; ++j) { b[j] = lo[j]; b[4 + j] = hi[j]; }
          bf[rr][p] = b;
        }
      __builtin_amdgcn_s_setprio(1);
#pragma unroll
      for (int ot = 0; ot < 4; ++ot)
#pragma unroll
        for (int rr = 0; rr < 2; ++rr)
#pragma unroll
          for (int p = 0; p < 4; ++p)
            acc[rr][ot][p] = __builtin_amdgcn_mfma_f32_16x16x32_bf16(
                afc[ot], bf[rr][p], acc[rr][ot][p], 0, 0, 0);
      __builtin_amdgcn_s_setprio(0);
      if (s < 24) {
#pragma unroll
        for (int ot = 0; ot < 4; ++ot) afc[ot] = afn[ot];
      }
    }
  }

  float* slds = FINAL ? (float*)xt : (float*)&xt[36864];

  if (FINAL) {
    // fp32 NCHW direct stores
    float* out = (float*)outp;
#pragma unroll
    for (int rr = 0; rr < 2; ++rr)
#pragma unroll
      for (int ot = 0; ot < 4; ++ot)
#pragma unroll
        for (int p = 0; p < 4; ++p)
#pragma unroll
          for (int r = 0; r < 4; ++r) {
            int oo = ot * 16 + quad * 4 + r;
            long off = ((long)(n * 64 + oo) << 16) + (r0 + w + rr * 4) * 256 + x0 + p * 16 + l15;
            out[off] = acc[rr][ot][p][r];
          }
    // ---- fused BN-stats partials ----
    __syncthreads();  // all xt reads done
#pragma unroll
    for (int ot = 0; ot < 4; ++ot)
#pragma unroll
      for (int r = 0; r < 4; ++r) {
        float s = 0.f, q = 0.f;
#pragma unroll
        for (int rr = 0; rr < 2; ++rr)
#pragma unroll
          for (int p = 0; p < 4; ++p) {
            float v = acc[rr][ot][p][r];
            s += v; q += v * v;
          }
#pragma unroll
        for (int m = 1; m < 16; m <<= 1) {
          s += __shfl_xor(s, m);
          q += __shfl_xor(q, m);
        }
        if (l15 == 0) {
          int ch = ot * 16 + quad * 4 + r;
          slds[w * 128 + ch] = s;
          slds[w * 128 + 64 + ch] = q;
        }
      }
    __syncthreads();
    if (tid < 128) {
      float v = slds[tid] + slds[128 + tid] + slds[256 + tid] + slds[384 + tid];
      partials[(long)tid * NB + bid] = v;
    }
  } else {
    __syncthreads();  // all xt reads done before aliasing
    // bf16 NHWC via LDS bounce (cbuf = xt[0..36863]) + stats into slds
    short* cbuf = xt;
#pragma unroll
    for (int rr = 0; rr < 2; ++rr)
#pragma unroll
      for (int ot = 0; ot < 4; ++ot)
#pragma unroll
        for (int p = 0; p < 4; ++p) {
          short4v pk;
#pragma unroll
          for (int r = 0; r < 4; ++r) pk[r] = f2bf_s(acc[rr][ot][p][r]);
          *(short4v*)&cbuf[((w + rr * 4) * 64 + p * 16 + l15) * 72 + ot * 16 + quad * 4] = pk;
        }
#pragma unroll
    for (int ot = 0; ot < 4; ++ot)
#pragma unroll
      for (int r = 0; r < 4; ++r) {
        float s = 0.f, q = 0.f;
#pragma unroll
        for (int rr = 0; rr < 2; ++rr)
#pragma unroll
          for (int p = 0; p < 4; ++p) {
            float v = acc[rr][ot][p][r];
            s += v; q += v * v;
          }
#pragma unroll
        for (int m = 1; m < 16; m <<= 1) {
          s += __shfl_xor(s, m);
          q += __shfl_xor(q, m);
        }
        if (l15 == 0) {
          int ch = ot * 16 + quad * 4 + r;
          slds[w * 128 + ch] = s;
          slds[w * 128 + 64 + ch] = q;
        }
      }
    __syncthreads();
    short* hout = (short*)outp;
    for (int idx = tid; idx < 4096; idx += 256) {
      int w2 = idx >> 9, rem = idx & 511;
      int px = rem >> 3, ch = rem & 7;
      short8 v = *(const short8*)&cbuf[(w2 * 64 + px) * 72 + ch * 8];
      *(short8*)&hout[(((long)(n * 256 + r0 + w2) * 256) + x0 + px) * 64 + ch * 8] = v;
    }
    if (tid < 128) {
      float v = slds[tid] + slds[128 + tid] + slds[256 + tid] + slds[384 + tid];
      partials[(long)tid * NB + bid] = v;
    }
  }
}

// ---------------- in-place BN + ReLU, fp32 NCHW, float4 grid-stride ----------------
__global__ __launch_bounds__(256) void bn_relu_f32v(float4* __restrict__ y,
                                                    const float* __restrict__ params) {
  const long total = (long)MK_N * MK_CO * MK_H * MK_W / 4;  // 8388608
  for (long i = (long)blockIdx.x * 256 + threadIdx.x; i < total;
       i += (long)gridDim.x * 256) {
    int ch = (int)((i >> 14) & (MK_CO - 1));  // 16384 float4 per (n,ch) plane
    float sc = params[ch], sh = params[MK_CO + ch];
    float4 v = y[i];
    v.x = fmaxf(fmaf(v.x, sc, sh), 0.f);
    v.y = fmaxf(fmaf(v.y, sc, sh), 0.f);
    v.z = fmaxf(fmaf(v.z, sc, sh), 0.f);
    v.w = fmaxf(fmaf(v.w, sc, sh), 0.f);
    y[i] = v;
  }
}

extern "C" void kernel_launch(void* const* d_in, const int* in_sizes, int n_in,
                              void* d_out, int out_size, void* d_ws, size_t ws_size,
                              hipStream_t stream) {
  const void* x     = d_in[0];
  const void* t     = d_in[1];
  const void* w5_1  = d_in[2];
  const void* w3_1  = d_in[3];
  const void* w1_1  = d_in[4];
  const void* a3_1  = d_in[5];
  const void* a5_1  = d_in[6];
  const void* gw_1  = d_in[7];
  const void* gb_1  = d_in[8];
  const void* gamma_1 = d_in[9];
  const void* beta_1  = d_in[10];
  const void* w5_2  = d_in[11];
  const void* w3_2  = d_in[12];
  const void* w1_2  = d_in[13];
  const void* a3_2  = d_in[14];
  const void* a5_2  = d_in[15];
  const void* gw_2  = d_in[16];
  const void* gb_2  = d_in[17];
  const void* gamma_2 = d_in[18];
  const void* beta_2  = d_in[19];

  // Memory map (d_out = 128 MiB, ws = 64 MiB):
  //   d_out[32M+4K]       : partials1 (512KB; consumed by reduce_finalize1)
  //   d_out[34M]          : P1 panels (819200 B, dead after conv1)
  //   d_out[100M]         : P2 panels (1638400 B) + pr1_hi (512 B) right after
  //   d_out[126M]         : partials2a (256KB; reduced before conv2B clobbers)
  //   d_out[0:128M)       : final fp32 NCHW out (conv2A n0-3 -> [0,64M),
  //                         conv2B n4-7 -> [64M,128M))
  //   ws[0:64M)           : h bf16 NHWC. After conv2A, ws[0:32M) (n0-3) dead:
  //   ws[0]: st2/pr2      ws[4K]: partials2b (256KB)   ws[2M]: P2+pr1 copy
  char* dob = (char*)d_out;
  float* part1 = (float*)(dob + 33554432 + 4096);
  short* P1    = (short*)(dob + 35651584);
  short* P2    = (short*)(dob + 104857600);
  float* pr1_hi = (float*)(dob + 104857600 + 1638400);
  float* part2a = (float*)(dob + 132120576);  // 126 MiB
  float* out = (float*)d_out;

  char* wsb = (char*)d_ws;
  short* h     = (short*)d_ws;
  float* st2   = (float*)d_ws;
  float* pr2   = st2 + 128;
  float* part2b = (float*)(wsb + 4096);
  short* P2c   = (short*)(wsb + 2097152);
  float* pr1c  = (float*)(wsb + 2097152 + 1638400);

  // ---- panels (both layers depend only on t + weight inputs) ----
  make_panels_dual<<<dim3(25, 8, 2), 256, 0, stream>>>(
      t, gw_1, gb_1, w5_1, w3_1, w1_1, a3_1, a5_1, P1,
      gw_2, gb_2, w5_2, w3_2, w1_2, a3_2, a5_2, P2, x);

  // ---- layer 1 (reads NCHW x directly; transpose fused into staging) ----
  conv_mfma<32, false, false, true><<<dim3(4, 32, 8), 256, 0, stream>>>(
      x, x, P1, h, 0, nullptr, part1, 1024);
  reduce_finalize<<<64, 256, 0, stream>>>(part1, 1024, nullptr, nullptr,
                                          pr1_hi, gamma_1, beta_1, x);

  // ---- layer 2 (layer-1 BN+ReLU fused into staging; split halves so panels /
  //      partials are never read after being overwritten) ----
  conv_mfma<64, true, true, false><<<dim3(4, 32, 4), 256, 0, stream>>>(
      h, x, P2, out, 0, pr1_hi, part2a, 512);
  reduce_finalize<<<64, 256, 0, stream>>>(part2a, 512, nullptr, st2,
                                          nullptr, nullptr, nullptr, x);
  copy16<<<401, 256, 0, stream>>>((const short8*)P2, (short8*)P2c, 102432);  // P2 + pr1
  conv_mfma<64, true, true, false><<<dim3(4, 32, 4), 256, 0, stream>>>(
      h, x, P2c, out, 4, pr1c, part2b, 512);
  reduce_finalize<<<64, 256, 0, stream>>>(part2b, 512, st2, nullptr,
                                          pr2, gamma_2, beta_2, x);
  bn_relu_f32v<<<4096, 256, 0, stream>>>((float4*)out, pr2);
}